// Round 1
// baseline (841.065 us; speedup 1.0000x reference)
//
#include <hip/hip_runtime.h>
#include <hip/hip_bf16.h>
#include <math.h>

#define TP_D   896
#define TP_H   8
#define TP_HD  112
#define TP_LQ  1568
#define TP_LK  6272
#define TP_D4  3584
#define TP_F   32
#define TP_P   196

typedef unsigned short u16;
typedef float f32x4 __attribute__((ext_vector_type(4)));
typedef __bf16 bf16x8 __attribute__((ext_vector_type(8)));

__device__ inline float bf2f(u16 u) {
    return __uint_as_float(((unsigned int)u) << 16);
}
__device__ inline u16 f2bf(float f) {
    unsigned int x = __float_as_uint(f);
    unsigned int lsb = (x >> 16) & 1u;
    x += 0x7fffu + lsb;
    return (u16)(x >> 16);
}

// ---------------------------------------------------------------- casts
__global__ void cast_f32_bf16(const float* __restrict__ src, u16* __restrict__ dst, int n) {
    int i = (blockIdx.x * blockDim.x + threadIdx.x) * 4;
    if (i + 3 < n) {
        float4 v = *(const float4*)(src + i);
        u16 o0 = f2bf(v.x), o1 = f2bf(v.y), o2 = f2bf(v.z), o3 = f2bf(v.w);
        ushort4 o = make_ushort4(o0, o1, o2, o3);
        *(ushort4*)(dst + i) = o;
    } else {
        for (; i < n; ++i) dst[i] = f2bf(src[i]);
    }
}

// src fp32 [R][C] -> dst bf16 [C][R].  R,C multiples of 32. block (32,8)
__global__ void transpose_cast(const float* __restrict__ src, u16* __restrict__ dst, int R, int C) {
    __shared__ float t[32][33];
    int bx = blockIdx.x * 32;  // col tile in src
    int by = blockIdx.y * 32;  // row tile in src
    int tx = threadIdx.x, ty = threadIdx.y;
#pragma unroll
    for (int j = 0; j < 4; ++j)
        t[ty + j * 8][tx] = src[(size_t)(by + ty + j * 8) * C + bx + tx];
    __syncthreads();
#pragma unroll
    for (int j = 0; j < 4; ++j)
        dst[(size_t)(bx + ty + j * 8) * R + by + tx] = f2bf(t[tx][ty + j * 8]);
}

// src bf16 [R][C] -> dst bf16 [C][R], per z slice of R*C
__global__ void transpose_bf16(const u16* __restrict__ src, u16* __restrict__ dst, int R, int C) {
    __shared__ u16 t[32][33];
    size_t zoff = (size_t)blockIdx.z * R * C;
    src += zoff; dst += zoff;
    int bx = blockIdx.x * 32, by = blockIdx.y * 32;
    int tx = threadIdx.x, ty = threadIdx.y;
#pragma unroll
    for (int j = 0; j < 4; ++j)
        t[ty + j * 8][tx] = src[(size_t)(by + ty + j * 8) * C + bx + tx];
    __syncthreads();
#pragma unroll
    for (int j = 0; j < 4; ++j)
        dst[(size_t)(bx + ty + j * 8) * R + by + tx] = t[tx][ty + j * 8];
}

// ---------------------------------------------------------------- GEMM
// C[M,N] = A[M,K] @ B[K,N], A row-major bf16 (lda), B supplied TRANSPOSED:
// Bt[n][k] row-major bf16 (ldb).  128x128 tile, BK=32, 4 waves (2x2 of 64x64),
// mfma_f32_16x16x32_bf16.  K need not be a multiple of 32 (zero-filled in LDS
// per 8-wide chunk; requires K % 8 == 0).
// MODE 1: out bf16 = acc*scale            at outB + z*cZ + row*ldc + col
// MODE 2: out bf16 = acc (col<N only)     at outB + row*896 + (hbase+z)*112 + col
// MODE 3: out f32  = acc + bias[col] + res[row*ldc+col]  at outF + row*ldc + col
// MODE 4: out bf16 = acc + bias[col] (relu optional)     at outB + row*ldc + col
struct GemmParams {
    const u16* A;  long long aZ; int lda;
    const u16* Bt; long long bZ; int ldb;
    int M, N, K;
    const float* bias;
    const float* res;
    float* outF;
    u16* outB; long long cZ; int ldc;
    float scale;
    int hbase;
    int relu;
};

#define LDS_STRIDE 56   // bf16 elems; 112B row: 16B-aligned, ~2-way banks

template <int MODE>
__global__ __launch_bounds__(256, 2) void gemm_bf16(GemmParams p) {
    __shared__ u16 lsA[128 * LDS_STRIDE];
    __shared__ u16 lsB[128 * LDS_STRIDE];

    const int tid = threadIdx.x;
    const int z = blockIdx.z;
    const u16* A  = p.A  + (size_t)z * p.aZ;
    const u16* Bt = p.Bt + (size_t)z * p.bZ;
    const int m0 = blockIdx.y * 128;
    const int n0 = blockIdx.x * 128;

    const int lane = tid & 63;
    const int w = tid >> 6;
    const int wm = (w >> 1) * 64, wn = (w & 1) * 64;
    const int c = lane & 15, q = lane >> 4;

    f32x4 acc[4][4];
#pragma unroll
    for (int i = 0; i < 4; ++i)
#pragma unroll
        for (int j = 0; j < 4; ++j) acc[i][j] = 0.f;

    const int r0 = tid >> 2;          // 0..63
    const int c8 = (tid & 3) * 8;     // 0,8,16,24
    int arow0 = m0 + r0;      if (arow0 >= p.M) arow0 = p.M - 1;
    int arow1 = m0 + r0 + 64; if (arow1 >= p.M) arow1 = p.M - 1;
    int brow0 = n0 + r0;      if (brow0 >= p.N) brow0 = p.N - 1;
    int brow1 = n0 + r0 + 64; if (brow1 >= p.N) brow1 = p.N - 1;
    const u16* a0 = A  + (size_t)arow0 * p.lda + c8;
    const u16* a1 = A  + (size_t)arow1 * p.lda + c8;
    const u16* b0 = Bt + (size_t)brow0 * p.ldb + c8;
    const u16* b1 = Bt + (size_t)brow1 * p.ldb + c8;

    const int KT = (p.K + 31) >> 5;
    for (int kt = 0; kt < KT; ++kt) {
        const int k0 = kt << 5;
        const bool valid = (k0 + c8 + 8) <= p.K;   // K % 8 == 0 guaranteed
        uint4 zv = make_uint4(0, 0, 0, 0);
        uint4 va0 = valid ? *(const uint4*)(a0 + k0) : zv;
        uint4 va1 = valid ? *(const uint4*)(a1 + k0) : zv;
        uint4 vb0 = valid ? *(const uint4*)(b0 + k0) : zv;
        uint4 vb1 = valid ? *(const uint4*)(b1 + k0) : zv;
        *(uint4*)(&lsA[r0 * LDS_STRIDE + c8])        = va0;
        *(uint4*)(&lsA[(r0 + 64) * LDS_STRIDE + c8]) = va1;
        *(uint4*)(&lsB[r0 * LDS_STRIDE + c8])        = vb0;
        *(uint4*)(&lsB[(r0 + 64) * LDS_STRIDE + c8]) = vb1;
        __syncthreads();

        bf16x8 af[4], bfv[4];
#pragma unroll
        for (int mi = 0; mi < 4; ++mi)
            af[mi] = *(const bf16x8*)(&lsA[(wm + mi * 16 + c) * LDS_STRIDE + q * 8]);
#pragma unroll
        for (int ni = 0; ni < 4; ++ni)
            bfv[ni] = *(const bf16x8*)(&lsB[(wn + ni * 16 + c) * LDS_STRIDE + q * 8]);
#pragma unroll
        for (int mi = 0; mi < 4; ++mi)
#pragma unroll
            for (int ni = 0; ni < 4; ++ni)
                acc[mi][ni] = __builtin_amdgcn_mfma_f32_16x16x32_bf16(af[mi], bfv[ni], acc[mi][ni], 0, 0, 0);
        __syncthreads();
    }

    // epilogue: C/D layout col = lane&15, row = quad*4 + reg   [m89-verified]
#pragma unroll
    for (int mi = 0; mi < 4; ++mi) {
#pragma unroll
        for (int r = 0; r < 4; ++r) {
            const int row = m0 + wm + mi * 16 + q * 4 + r;
            if (row >= p.M) continue;
#pragma unroll
            for (int ni = 0; ni < 4; ++ni) {
                const int col = n0 + wn + ni * 16 + c;
                float v = acc[mi][ni][r];
                if (MODE == 1) {
                    v *= p.scale;
                    p.outB[(size_t)z * p.cZ + (size_t)row * p.ldc + col] = f2bf(v);
                } else if (MODE == 2) {
                    if (col < p.N)
                        p.outB[(size_t)row * TP_D + (p.hbase + z) * TP_HD + col] = f2bf(v);
                } else if (MODE == 3) {
                    v += p.bias[col] + p.res[(size_t)row * p.ldc + col];
                    p.outF[(size_t)row * p.ldc + col] = v;
                } else if (MODE == 4) {
                    v += p.bias[col];
                    if (p.relu) v = v > 0.f ? v : 0.f;
                    p.outB[(size_t)row * p.ldc + col] = f2bf(v);
                }
            }
        }
    }
}

// ---------------------------------------------------------------- softmax
// one block per (head,query) row of 6272 bf16 scores; in-place -> probs
__global__ __launch_bounds__(256) void softmax_rows(u16* __restrict__ S) {
    const int tid = threadIdx.x;
    u16* row = S + (size_t)blockIdx.x * TP_LK;
    float v[25];
#pragma unroll
    for (int i = 0; i < 25; ++i) {
        int idx = tid + i * 256;
        v[i] = (idx < TP_LK) ? bf2f(row[idx]) : -1e30f;
    }
    float m = -1e30f;
#pragma unroll
    for (int i = 0; i < 25; ++i) m = fmaxf(m, v[i]);
    __shared__ float red[4];
#pragma unroll
    for (int o = 32; o > 0; o >>= 1) m = fmaxf(m, __shfl_xor(m, o, 64));
    if ((tid & 63) == 0) red[tid >> 6] = m;
    __syncthreads();
    m = fmaxf(fmaxf(red[0], red[1]), fmaxf(red[2], red[3]));
    __syncthreads();
    float s = 0.f;
#pragma unroll
    for (int i = 0; i < 25; ++i) s += __expf(v[i] - m);
#pragma unroll
    for (int o = 32; o > 0; o >>= 1) s += __shfl_xor(s, o, 64);
    if ((tid & 63) == 0) red[tid >> 6] = s;
    __syncthreads();
    s = red[0] + red[1] + red[2] + red[3];
    const float inv = 1.f / s;
#pragma unroll
    for (int i = 0; i < 25; ++i) {
        int idx = tid + i * 256;
        if (idx < TP_LK) row[idx] = f2bf(__expf(v[i] - m) * inv);
    }
}

// colsum[k] += sum over rows of P[row][k]
__global__ void colsum_kernel(const u16* __restrict__ P, float* __restrict__ colsum, int nrows) {
    int cidx = blockIdx.x * 256 + threadIdx.x;
    if (cidx >= TP_LK) return;
    int chunk = (nrows + gridDim.y - 1) / gridDim.y;
    int r0 = blockIdx.y * chunk;
    int r1 = r0 + chunk; if (r1 > nrows) r1 = nrows;
    float acc = 0.f;
    for (int r = r0; r < r1; ++r) acc += bf2f(P[(size_t)r * TP_LK + cidx]);
    atomicAdd(&colsum[cidx], acc);
}

// ---------------------------------------------------------------- layernorm
__global__ __launch_bounds__(256) void layernorm_rows(const float* __restrict__ x,
        const float* __restrict__ g, const float* __restrict__ b,
        float* __restrict__ outF, u16* __restrict__ outB) {
    const int tid = threadIdx.x;
    const float* xr = x + (size_t)blockIdx.x * TP_D;
    float v[4];
#pragma unroll
    for (int i = 0; i < 4; ++i) {
        int idx = tid + i * 256;
        v[i] = (idx < TP_D) ? xr[idx] : 0.f;
    }
    float s = v[0] + v[1] + v[2] + v[3];
    __shared__ float red[4];
#pragma unroll
    for (int o = 32; o > 0; o >>= 1) s += __shfl_xor(s, o, 64);
    if ((tid & 63) == 0) red[tid >> 6] = s;
    __syncthreads();
    const float mu = (red[0] + red[1] + red[2] + red[3]) * (1.f / TP_D);
    __syncthreads();
    float ss = 0.f;
#pragma unroll
    for (int i = 0; i < 4; ++i) {
        int idx = tid + i * 256;
        if (idx < TP_D) { float d = v[i] - mu; ss += d * d; }
    }
#pragma unroll
    for (int o = 32; o > 0; o >>= 1) ss += __shfl_xor(ss, o, 64);
    if ((tid & 63) == 0) red[tid >> 6] = ss;
    __syncthreads();
    const float var = (red[0] + red[1] + red[2] + red[3]) * (1.f / TP_D);
    const float rs = rsqrtf(var + 1e-12f);
    float* of = outF + (size_t)blockIdx.x * TP_D;
    u16* ob = outB ? outB + (size_t)blockIdx.x * TP_D : nullptr;
#pragma unroll
    for (int i = 0; i < 4; ++i) {
        int idx = tid + i * 256;
        if (idx < TP_D) {
            float y = (v[i] - mu) * rs * g[idx] + b[idx];
            of[idx] = y;
            if (ob) ob[idx] = f2bf(y);
        }
    }
}

__global__ void frame_scores_kernel(const float* __restrict__ colsum, float* __restrict__ out) {
    const int tid = threadIdx.x;
    float v = (tid < TP_P) ? colsum[blockIdx.x * TP_P + tid] : 0.f;
    __shared__ float red[4];
#pragma unroll
    for (int o = 32; o > 0; o >>= 1) v += __shfl_xor(v, o, 64);
    if ((tid & 63) == 0) red[tid >> 6] = v;
    __syncthreads();
    if (tid == 0) out[blockIdx.x] = (red[0] + red[1] + red[2] + red[3]) * (1.f / TP_P);
}

// ---------------------------------------------------------------- launch
extern "C" void kernel_launch(void* const* d_in, const int* in_sizes, int n_in,
                              void* d_out, int out_size, void* d_ws, size_t ws_size,
                              hipStream_t stream) {
    const float* img  = (const float*)d_in[0];
    const float* mem  = (const float*)d_in[1];
    const float* qW   = (const float*)d_in[2];
    const float* qb   = (const float*)d_in[3];
    const float* kW   = (const float*)d_in[4];
    const float* kb   = (const float*)d_in[5];
    const float* vW   = (const float*)d_in[6];
    const float* vb   = (const float*)d_in[7];
    const float* oW   = (const float*)d_in[8];
    const float* ob   = (const float*)d_in[9];
    const float* ln1g = (const float*)d_in[10];
    const float* ln1b = (const float*)d_in[11];
    const float* mW   = (const float*)d_in[12];
    const float* mb   = (const float*)d_in[13];
    const float* pW   = (const float*)d_in[14];
    const float* pb   = (const float*)d_in[15];
    const float* ln2g = (const float*)d_in[16];
    const float* ln2b = (const float*)d_in[17];
    float* out = (float*)d_out;

    char* base = (char*)d_ws;
    size_t off = 0;
    auto take = [&](size_t nbytes) -> void* {
        void* p = base + off;
        off += (nbytes + 255) & ~(size_t)255;
        return p;
    };

    u16* imgB  = (u16*)take((size_t)TP_LK * TP_D * 2);
    u16* memB  = (u16*)take((size_t)TP_LQ * TP_D * 2);
    u16* qWt   = (u16*)take((size_t)TP_D * TP_D * 2);
    u16* kWt   = (u16*)take((size_t)TP_D * TP_D * 2);
    u16* vWt   = (u16*)take((size_t)TP_D * TP_D * 2);
    u16* oWt   = (u16*)take((size_t)TP_D * TP_D * 2);
    u16* mWt   = (u16*)take((size_t)TP_D * TP_D4 * 2);
    u16* pWt   = (u16*)take((size_t)TP_D * TP_D4 * 2);
    u16* Qf    = (u16*)take((size_t)TP_LQ * TP_D * 2);
    u16* Kf    = (u16*)take((size_t)TP_LK * TP_D * 2);
    u16* Vf    = (u16*)take((size_t)TP_LK * TP_D * 2);
    u16* Vtf   = (u16*)take((size_t)TP_LK * TP_D * 2);
    u16* ctxB  = (u16*)take((size_t)TP_LQ * TP_D * 2);
    float* pre1  = (float*)take((size_t)TP_LQ * TP_D * 4);
    float* attn  = (float*)take((size_t)TP_LQ * TP_D * 4);
    u16* attnB = (u16*)take((size_t)TP_LQ * TP_D * 2);
    u16* hidden= (u16*)take((size_t)TP_LQ * TP_D4 * 2);
    float* pre2  = (float*)take((size_t)TP_LQ * TP_D * 4);
    float* colsum= (float*)take((size_t)TP_LK * 4);

    const size_t perHeadS = (size_t)TP_LQ * TP_LK;           // elements
    const int hc = (ws_size >= off + 8 * perHeadS * 2 + 4096) ? 8 : 1;
    u16* S = (u16*)take((size_t)hc * perHeadS * 2);

    // ---- casts / transposes
    cast_f32_bf16<<<(TP_LK * TP_D / 4 + 255) / 256, 256, 0, stream>>>(img, imgB, TP_LK * TP_D);
    cast_f32_bf16<<<(TP_LQ * TP_D / 4 + 255) / 256, 256, 0, stream>>>(mem, memB, TP_LQ * TP_D);
    transpose_cast<<<dim3(28, 28), dim3(32, 8), 0, stream>>>(qW, qWt, TP_D, TP_D);
    transpose_cast<<<dim3(28, 28), dim3(32, 8), 0, stream>>>(kW, kWt, TP_D, TP_D);
    transpose_cast<<<dim3(28, 28), dim3(32, 8), 0, stream>>>(vW, vWt, TP_D, TP_D);
    transpose_cast<<<dim3(28, 28), dim3(32, 8), 0, stream>>>(oW, oWt, TP_D, TP_D);
    transpose_cast<<<dim3(TP_D4 / 32, TP_D / 32), dim3(32, 8), 0, stream>>>(mW, mWt, TP_D, TP_D4);
    transpose_cast<<<dim3(TP_D / 32, TP_D4 / 32), dim3(32, 8), 0, stream>>>(pW, pWt, TP_D4, TP_D);
    hipMemsetAsync(colsum, 0, (size_t)TP_LK * 4, stream);

    // ---- QKV projections (MODE 4, no relu)
    {
        GemmParams p{};
        p.A = memB; p.aZ = 0; p.lda = TP_D;
        p.Bt = qWt; p.bZ = 0; p.ldb = TP_D;
        p.M = TP_LQ; p.N = TP_D; p.K = TP_D;
        p.bias = qb; p.outB = Qf; p.ldc = TP_D; p.relu = 0;
        gemm_bf16<4><<<dim3(7, 13, 1), 256, 0, stream>>>(p);
    }
    {
        GemmParams p{};
        p.A = imgB; p.aZ = 0; p.lda = TP_D;
        p.Bt = kWt; p.bZ = 0; p.ldb = TP_D;
        p.M = TP_LK; p.N = TP_D; p.K = TP_D;
        p.bias = kb; p.outB = Kf; p.ldc = TP_D; p.relu = 0;
        gemm_bf16<4><<<dim3(7, 49, 1), 256, 0, stream>>>(p);
    }
    {
        GemmParams p{};
        p.A = imgB; p.aZ = 0; p.lda = TP_D;
        p.Bt = vWt; p.bZ = 0; p.ldb = TP_D;
        p.M = TP_LK; p.N = TP_D; p.K = TP_D;
        p.bias = vb; p.outB = Vf; p.ldc = TP_D; p.relu = 0;
        gemm_bf16<4><<<dim3(7, 49, 1), 256, 0, stream>>>(p);
    }
    // V^T for the PV gemm (Bt must be n-major)
    transpose_bf16<<<dim3(TP_D / 32, TP_LK / 32, 1), dim3(32, 8), 0, stream>>>(Vf, Vtf, TP_LK, TP_D);

    // ---- attention
    const float scale = 0.09449111825230679f;  // 1/sqrt(112)
    for (int h0 = 0; h0 < TP_H; h0 += hc) {
        {
            GemmParams p{};
            p.A = Qf + h0 * TP_HD; p.aZ = TP_HD; p.lda = TP_D;
            p.Bt = Kf + h0 * TP_HD; p.bZ = TP_HD; p.ldb = TP_D;
            p.M = TP_LQ; p.N = TP_LK; p.K = TP_HD;
            p.outB = S; p.cZ = (long long)TP_LQ * TP_LK; p.ldc = TP_LK;
            p.scale = scale;
            gemm_bf16<1><<<dim3(49, 13, hc), 256, 0, stream>>>(p);
        }
        softmax_rows<<<hc * TP_LQ, 256, 0, stream>>>(S);
        colsum_kernel<<<dim3(25, 32), 256, 0, stream>>>(S, colsum, hc * TP_LQ);
        {
            GemmParams p{};
            p.A = S; p.aZ = (long long)TP_LQ * TP_LK; p.lda = TP_LK;
            p.Bt = Vtf + (size_t)h0 * TP_HD * TP_LK; p.bZ = (long long)TP_HD * TP_LK; p.ldb = TP_LK;
            p.M = TP_LQ; p.N = TP_HD; p.K = TP_LK;
            p.outB = ctxB; p.hbase = h0;
            gemm_bf16<2><<<dim3(1, 13, hc), 256, 0, stream>>>(p);
        }
    }

    // ---- O-projection + residual (fp32) -> LN1
    {
        GemmParams p{};
        p.A = ctxB; p.aZ = 0; p.lda = TP_D;
        p.Bt = oWt; p.bZ = 0; p.ldb = TP_D;
        p.M = TP_LQ; p.N = TP_D; p.K = TP_D;
        p.bias = ob; p.res = mem; p.outF = pre1; p.ldc = TP_D;
        gemm_bf16<3><<<dim3(7, 13, 1), 256, 0, stream>>>(p);
    }
    layernorm_rows<<<TP_LQ, 256, 0, stream>>>(pre1, ln1g, ln1b, attn, attnB);

    // ---- MLP
    {
        GemmParams p{};
        p.A = attnB; p.aZ = 0; p.lda = TP_D;
        p.Bt = mWt; p.bZ = 0; p.ldb = TP_D;
        p.M = TP_LQ; p.N = TP_D4; p.K = TP_D;
        p.bias = mb; p.outB = hidden; p.ldc = TP_D4; p.relu = 1;
        gemm_bf16<4><<<dim3(28, 13, 1), 256, 0, stream>>>(p);
    }
    {
        GemmParams p{};
        p.A = hidden; p.aZ = 0; p.lda = TP_D4;
        p.Bt = pWt; p.bZ = 0; p.ldb = TP_D4;
        p.M = TP_LQ; p.N = TP_D; p.K = TP_D4;
        p.bias = pb; p.res = attn; p.outF = pre2; p.ldc = TP_D;
        gemm_bf16<3><<<dim3(7, 13, 1), 256, 0, stream>>>(p);
    }
    layernorm_rows<<<TP_LQ, 256, 0, stream>>>(pre2, ln2g, ln2b, out, nullptr);

    // ---- frame scores
    frame_scores_kernel<<<TP_F, 256, 0, stream>>>(colsum, out + (size_t)TP_LQ * TP_D);
}

// Round 2
// 752.580 us; speedup vs baseline: 1.1176x; 1.1176x over previous
//
#include <hip/hip_runtime.h>
#include <hip/hip_bf16.h>
#include <math.h>

#define TP_D   896
#define TP_H   8
#define TP_HD  112
#define TP_LQ  1568
#define TP_LK  6272
#define TP_D4  3584
#define TP_F   32
#define TP_P   196
#define PV_KS  7          // split-K factor for PV gemm (6272 = 7*896)
#define PV_KC  896

typedef unsigned short u16;
typedef float f32x4 __attribute__((ext_vector_type(4)));
typedef __bf16 bf16x8 __attribute__((ext_vector_type(8)));

__device__ inline float bf2f(u16 u) {
    return __uint_as_float(((unsigned int)u) << 16);
}
__device__ inline u16 f2bf(float f) {
    unsigned int x = __float_as_uint(f);
    unsigned int lsb = (x >> 16) & 1u;
    x += 0x7fffu + lsb;
    return (u16)(x >> 16);
}

// ---------------------------------------------------------------- casts
__global__ void cast_f32_bf16(const float* __restrict__ src, u16* __restrict__ dst, int n) {
    int i = (blockIdx.x * blockDim.x + threadIdx.x) * 4;
    if (i + 3 < n) {
        float4 v = *(const float4*)(src + i);
        u16 o0 = f2bf(v.x), o1 = f2bf(v.y), o2 = f2bf(v.z), o3 = f2bf(v.w);
        ushort4 o = make_ushort4(o0, o1, o2, o3);
        *(ushort4*)(dst + i) = o;
    } else {
        for (; i < n; ++i) dst[i] = f2bf(src[i]);
    }
}

// src fp32 [R][C] -> dst bf16 [C][R].  R,C multiples of 32. block (32,8)
__global__ void transpose_cast(const float* __restrict__ src, u16* __restrict__ dst, int R, int C) {
    __shared__ float t[32][33];
    int bx = blockIdx.x * 32;
    int by = blockIdx.y * 32;
    int tx = threadIdx.x, ty = threadIdx.y;
#pragma unroll
    for (int j = 0; j < 4; ++j)
        t[ty + j * 8][tx] = src[(size_t)(by + ty + j * 8) * C + bx + tx];
    __syncthreads();
#pragma unroll
    for (int j = 0; j < 4; ++j)
        dst[(size_t)(bx + ty + j * 8) * R + by + tx] = f2bf(t[tx][ty + j * 8]);
}

// src bf16 [R][C] -> dst bf16 [C][R]
__global__ void transpose_bf16(const u16* __restrict__ src, u16* __restrict__ dst, int R, int C) {
    __shared__ u16 t[32][33];
    size_t zoff = (size_t)blockIdx.z * R * C;
    src += zoff; dst += zoff;
    int bx = blockIdx.x * 32, by = blockIdx.y * 32;
    int tx = threadIdx.x, ty = threadIdx.y;
#pragma unroll
    for (int j = 0; j < 4; ++j)
        t[ty + j * 8][tx] = src[(size_t)(by + ty + j * 8) * C + bx + tx];
    __syncthreads();
#pragma unroll
    for (int j = 0; j < 4; ++j)
        dst[(size_t)(bx + ty + j * 8) * R + by + tx] = t[tx][ty + j * 8];
}

// ---------------------------------------------------------------- GEMM
// C[M,N] = A[M,K] @ Bt[N,K]^T, 128x128 tile, BK=32, mfma_f32_16x16x32_bf16.
// MODE 1: out bf16 = acc*scale  at outB + z*cZ + row*ldc + col      (S gemm)
// MODE 3: out f32  = acc + bias[col] + res[row*ldc+col]             (proj+res)
// MODE 4: out bf16 = acc + bias[col] (relu optional)                (QKV / MLP1)
// MODE 5: split-K PV: z -> (relhead, ks); atomicAdd fp32 into
//         outF[row*896 + (hbase+relhead)*112 + col], col < N
struct GemmParams {
    const u16* A;  long long aZ; int lda;
    const u16* Bt; long long bZ; int ldb;
    int M, N, K;
    const float* bias;
    const float* res;
    float* outF;
    u16* outB; long long cZ; int ldc;
    float scale;
    int hbase;
    int relu;
};

#define LDS_STRIDE 56   // bf16 elems

template <int MODE>
__global__ __launch_bounds__(256, 2) void gemm_bf16(GemmParams p) {
    __shared__ u16 lsA[128 * LDS_STRIDE];
    __shared__ u16 lsB[128 * LDS_STRIDE];

    const int tid = threadIdx.x;
    const int z = blockIdx.z;
    const u16* A;
    const u16* Bt;
    int abshead = 0;
    if (MODE == 5) {
        const int rel = z / PV_KS;
        const int ks = z - rel * PV_KS;
        abshead = p.hbase + rel;
        A  = p.A  + (size_t)rel * p.aZ + (size_t)ks * PV_KC;
        Bt = p.Bt + (size_t)abshead * p.bZ + (size_t)ks * PV_KC;
    } else {
        A  = p.A  + (size_t)z * p.aZ;
        Bt = p.Bt + (size_t)z * p.bZ;
    }
    const int m0 = blockIdx.y * 128;
    const int n0 = blockIdx.x * 128;

    const int lane = tid & 63;
    const int w = tid >> 6;
    const int wm = (w >> 1) * 64, wn = (w & 1) * 64;
    const int c = lane & 15, q = lane >> 4;

    f32x4 acc[4][4];
#pragma unroll
    for (int i = 0; i < 4; ++i)
#pragma unroll
        for (int j = 0; j < 4; ++j) acc[i][j] = 0.f;

    const int r0 = tid >> 2;
    const int c8 = (tid & 3) * 8;
    int arow0 = m0 + r0;      if (arow0 >= p.M) arow0 = p.M - 1;
    int arow1 = m0 + r0 + 64; if (arow1 >= p.M) arow1 = p.M - 1;
    int brow0 = n0 + r0;      if (brow0 >= p.N) brow0 = p.N - 1;
    int brow1 = n0 + r0 + 64; if (brow1 >= p.N) brow1 = p.N - 1;
    const u16* a0 = A  + (size_t)arow0 * p.lda + c8;
    const u16* a1 = A  + (size_t)arow1 * p.lda + c8;
    const u16* b0 = Bt + (size_t)brow0 * p.ldb + c8;
    const u16* b1 = Bt + (size_t)brow1 * p.ldb + c8;

    const int KT = (p.K + 31) >> 5;
    for (int kt = 0; kt < KT; ++kt) {
        const int k0 = kt << 5;
        const bool valid = (k0 + c8 + 8) <= p.K;
        uint4 zv = make_uint4(0, 0, 0, 0);
        uint4 va0 = valid ? *(const uint4*)(a0 + k0) : zv;
        uint4 va1 = valid ? *(const uint4*)(a1 + k0) : zv;
        uint4 vb0 = valid ? *(const uint4*)(b0 + k0) : zv;
        uint4 vb1 = valid ? *(const uint4*)(b1 + k0) : zv;
        *(uint4*)(&lsA[r0 * LDS_STRIDE + c8])        = va0;
        *(uint4*)(&lsA[(r0 + 64) * LDS_STRIDE + c8]) = va1;
        *(uint4*)(&lsB[r0 * LDS_STRIDE + c8])        = vb0;
        *(uint4*)(&lsB[(r0 + 64) * LDS_STRIDE + c8]) = vb1;
        __syncthreads();

        bf16x8 af[4], bfv[4];
#pragma unroll
        for (int mi = 0; mi < 4; ++mi)
            af[mi] = *(const bf16x8*)(&lsA[(wm + mi * 16 + c) * LDS_STRIDE + q * 8]);
#pragma unroll
        for (int ni = 0; ni < 4; ++ni)
            bfv[ni] = *(const bf16x8*)(&lsB[(wn + ni * 16 + c) * LDS_STRIDE + q * 8]);
#pragma unroll
        for (int mi = 0; mi < 4; ++mi)
#pragma unroll
            for (int ni = 0; ni < 4; ++ni)
                acc[mi][ni] = __builtin_amdgcn_mfma_f32_16x16x32_bf16(af[mi], bfv[ni], acc[mi][ni], 0, 0, 0);
        __syncthreads();
    }

    // epilogue: C/D layout col = lane&15, row = quad*4 + reg
#pragma unroll
    for (int mi = 0; mi < 4; ++mi) {
#pragma unroll
        for (int r = 0; r < 4; ++r) {
            const int row = m0 + wm + mi * 16 + q * 4 + r;
            if (row >= p.M) continue;
#pragma unroll
            for (int ni = 0; ni < 4; ++ni) {
                const int col = n0 + wn + ni * 16 + c;
                float v = acc[mi][ni][r];
                if (MODE == 1) {
                    v *= p.scale;
                    p.outB[(size_t)z * p.cZ + (size_t)row * p.ldc + col] = f2bf(v);
                } else if (MODE == 3) {
                    v += p.bias[col] + p.res[(size_t)row * p.ldc + col];
                    p.outF[(size_t)row * p.ldc + col] = v;
                } else if (MODE == 4) {
                    v += p.bias[col];
                    if (p.relu) v = v > 0.f ? v : 0.f;
                    p.outB[(size_t)row * p.ldc + col] = f2bf(v);
                } else if (MODE == 5) {
                    if (col < p.N)
                        atomicAdd(&p.outF[(size_t)row * TP_D + abshead * TP_HD + col], v);
                }
            }
        }
    }
}

// ---------------------------------------------------------------- softmax
// one block per (head,query) row of 6272 bf16 scores; in-place -> probs
__global__ __launch_bounds__(256) void softmax_rows(u16* __restrict__ S) {
    const int tid = threadIdx.x;
    u16* row = S + (size_t)blockIdx.x * TP_LK;
    const ushort4* row4 = (const ushort4*)row;
    float v[28];
#pragma unroll
    for (int i = 0; i < 7; ++i) {
        int idx = tid + i * 256;
        if (idx < 1568) {
            ushort4 u = row4[idx];
            v[4 * i + 0] = bf2f(u.x); v[4 * i + 1] = bf2f(u.y);
            v[4 * i + 2] = bf2f(u.z); v[4 * i + 3] = bf2f(u.w);
        }
    }
    float m = -1e30f;
#pragma unroll
    for (int i = 0; i < 7; ++i) {
        int idx = tid + i * 256;
        if (idx < 1568) {
            m = fmaxf(m, fmaxf(fmaxf(v[4 * i], v[4 * i + 1]), fmaxf(v[4 * i + 2], v[4 * i + 3])));
        }
    }
    __shared__ float red[4];
#pragma unroll
    for (int o = 32; o > 0; o >>= 1) m = fmaxf(m, __shfl_xor(m, o, 64));
    if ((tid & 63) == 0) red[tid >> 6] = m;
    __syncthreads();
    m = fmaxf(fmaxf(red[0], red[1]), fmaxf(red[2], red[3]));
    __syncthreads();
    float s = 0.f;
#pragma unroll
    for (int i = 0; i < 7; ++i) {
        int idx = tid + i * 256;
        if (idx < 1568) {
#pragma unroll
            for (int j = 0; j < 4; ++j) {
                v[4 * i + j] = __expf(v[4 * i + j] - m);
                s += v[4 * i + j];
            }
        }
    }
#pragma unroll
    for (int o = 32; o > 0; o >>= 1) s += __shfl_xor(s, o, 64);
    if ((tid & 63) == 0) red[tid >> 6] = s;
    __syncthreads();
    s = red[0] + red[1] + red[2] + red[3];
    const float inv = 1.f / s;
    ushort4* wrow4 = (ushort4*)row;
#pragma unroll
    for (int i = 0; i < 7; ++i) {
        int idx = tid + i * 256;
        if (idx < 1568) {
            ushort4 o;
            o.x = f2bf(v[4 * i + 0] * inv); o.y = f2bf(v[4 * i + 1] * inv);
            o.z = f2bf(v[4 * i + 2] * inv); o.w = f2bf(v[4 * i + 3] * inv);
            wrow4[idx] = o;
        }
    }
}

// colsum[k] += sum over rows of P[row][k]; vec4 columns per thread
__global__ void colsum_kernel(const u16* __restrict__ P, float* __restrict__ colsum, int nrows) {
    int c4 = blockIdx.x * 256 + threadIdx.x;   // vec4 col index, 0..1567
    if (c4 >= TP_LK / 4) return;
    int chunk = (nrows + gridDim.y - 1) / gridDim.y;
    int r0 = blockIdx.y * chunk;
    int r1 = r0 + chunk; if (r1 > nrows) r1 = nrows;
    float a0 = 0.f, a1 = 0.f, a2 = 0.f, a3 = 0.f;
    for (int r = r0; r < r1; ++r) {
        ushort4 u = ((const ushort4*)(P + (size_t)r * TP_LK))[c4];
        a0 += bf2f(u.x); a1 += bf2f(u.y); a2 += bf2f(u.z); a3 += bf2f(u.w);
    }
    atomicAdd(&colsum[4 * c4 + 0], a0);
    atomicAdd(&colsum[4 * c4 + 1], a1);
    atomicAdd(&colsum[4 * c4 + 2], a2);
    atomicAdd(&colsum[4 * c4 + 3], a3);
}

// ---------------------------------------------------------------- layernorm
__global__ __launch_bounds__(256) void layernorm_rows(const float* __restrict__ x,
        const float* __restrict__ g, const float* __restrict__ b,
        float* __restrict__ outF, u16* __restrict__ outB) {
    const int tid = threadIdx.x;
    const float* xr = x + (size_t)blockIdx.x * TP_D;
    float v[4];
#pragma unroll
    for (int i = 0; i < 4; ++i) {
        int idx = tid + i * 256;
        v[i] = (idx < TP_D) ? xr[idx] : 0.f;
    }
    float s = v[0] + v[1] + v[2] + v[3];
    __shared__ float red[4];
#pragma unroll
    for (int o = 32; o > 0; o >>= 1) s += __shfl_xor(s, o, 64);
    if ((tid & 63) == 0) red[tid >> 6] = s;
    __syncthreads();
    const float mu = (red[0] + red[1] + red[2] + red[3]) * (1.f / TP_D);
    __syncthreads();
    float ss = 0.f;
#pragma unroll
    for (int i = 0; i < 4; ++i) {
        int idx = tid + i * 256;
        if (idx < TP_D) { float d = v[i] - mu; ss += d * d; }
    }
#pragma unroll
    for (int o = 32; o > 0; o >>= 1) ss += __shfl_xor(ss, o, 64);
    if ((tid & 63) == 0) red[tid >> 6] = ss;
    __syncthreads();
    const float var = (red[0] + red[1] + red[2] + red[3]) * (1.f / TP_D);
    const float rs = rsqrtf(var + 1e-12f);
    float* of = outF + (size_t)blockIdx.x * TP_D;
    u16* ob = outB ? outB + (size_t)blockIdx.x * TP_D : nullptr;
#pragma unroll
    for (int i = 0; i < 4; ++i) {
        int idx = tid + i * 256;
        if (idx < TP_D) {
            float y = (v[i] - mu) * rs * g[idx] + b[idx];
            of[idx] = y;
            if (ob) ob[idx] = f2bf(y);
        }
    }
}

__global__ void frame_scores_kernel(const float* __restrict__ colsum, float* __restrict__ out) {
    const int tid = threadIdx.x;
    float v = (tid < TP_P) ? colsum[blockIdx.x * TP_P + tid] : 0.f;
    __shared__ float red[4];
#pragma unroll
    for (int o = 32; o > 0; o >>= 1) v += __shfl_xor(v, o, 64);
    if ((tid & 63) == 0) red[tid >> 6] = v;
    __syncthreads();
    if (tid == 0) out[blockIdx.x] = (red[0] + red[1] + red[2] + red[3]) * (1.f / TP_P);
}

// ---------------------------------------------------------------- launch
extern "C" void kernel_launch(void* const* d_in, const int* in_sizes, int n_in,
                              void* d_out, int out_size, void* d_ws, size_t ws_size,
                              hipStream_t stream) {
    const float* img  = (const float*)d_in[0];
    const float* mem  = (const float*)d_in[1];
    const float* qW   = (const float*)d_in[2];
    const float* qb   = (const float*)d_in[3];
    const float* kW   = (const float*)d_in[4];
    const float* kb   = (const float*)d_in[5];
    const float* vW   = (const float*)d_in[6];
    const float* vb   = (const float*)d_in[7];
    const float* oW   = (const float*)d_in[8];
    const float* ob   = (const float*)d_in[9];
    const float* ln1g = (const float*)d_in[10];
    const float* ln1b = (const float*)d_in[11];
    const float* mW   = (const float*)d_in[12];
    const float* mb   = (const float*)d_in[13];
    const float* pW   = (const float*)d_in[14];
    const float* pb   = (const float*)d_in[15];
    const float* ln2g = (const float*)d_in[16];
    const float* ln2b = (const float*)d_in[17];
    float* out = (float*)d_out;

    char* base = (char*)d_ws;
    size_t off = 0;
    auto take = [&](size_t nbytes) -> void* {
        void* p = base + off;
        off += (nbytes + 255) & ~(size_t)255;
        return p;
    };

    u16* imgB  = (u16*)take((size_t)TP_LK * TP_D * 2);
    u16* memB  = (u16*)take((size_t)TP_LQ * TP_D * 2);
    u16* qWt   = (u16*)take((size_t)TP_D * TP_D * 2);
    u16* kWt   = (u16*)take((size_t)TP_D * TP_D * 2);
    u16* vWt   = (u16*)take((size_t)TP_D * TP_D * 2);
    u16* oWt   = (u16*)take((size_t)TP_D * TP_D * 2);
    u16* mWt   = (u16*)take((size_t)TP_D * TP_D4 * 2);
    u16* pWt   = (u16*)take((size_t)TP_D * TP_D4 * 2);
    u16* Qf    = (u16*)take((size_t)TP_LQ * TP_D * 2);
    u16* Kf    = (u16*)take((size_t)TP_LK * TP_D * 2);
    u16* Vf    = (u16*)take((size_t)TP_LK * TP_D * 2);
    u16* Vtf   = (u16*)take((size_t)TP_LK * TP_D * 2);
    float* ctxF  = (float*)take((size_t)TP_LQ * TP_D * 4);
    u16* ctxB  = (u16*)take((size_t)TP_LQ * TP_D * 2);
    float* pre1  = (float*)take((size_t)TP_LQ * TP_D * 4);
    float* attn  = (float*)take((size_t)TP_LQ * TP_D * 4);
    u16* attnB = (u16*)take((size_t)TP_LQ * TP_D * 2);
    u16* hidden= (u16*)take((size_t)TP_LQ * TP_D4 * 2);
    float* pre2  = (float*)take((size_t)TP_LQ * TP_D * 4);
    float* colsum= (float*)take((size_t)TP_LK * 4);

    const size_t perHeadS = (size_t)TP_LQ * TP_LK;
    const int hc = (ws_size >= off + 8 * perHeadS * 2 + 4096) ? 8 : 1;
    u16* S = (u16*)take((size_t)hc * perHeadS * 2);

    // ---- casts / transposes
    cast_f32_bf16<<<(TP_LK * TP_D / 4 + 255) / 256, 256, 0, stream>>>(img, imgB, TP_LK * TP_D);
    cast_f32_bf16<<<(TP_LQ * TP_D / 4 + 255) / 256, 256, 0, stream>>>(mem, memB, TP_LQ * TP_D);
    transpose_cast<<<dim3(28, 28), dim3(32, 8), 0, stream>>>(qW, qWt, TP_D, TP_D);
    transpose_cast<<<dim3(28, 28), dim3(32, 8), 0, stream>>>(kW, kWt, TP_D, TP_D);
    transpose_cast<<<dim3(28, 28), dim3(32, 8), 0, stream>>>(vW, vWt, TP_D, TP_D);
    transpose_cast<<<dim3(28, 28), dim3(32, 8), 0, stream>>>(oW, oWt, TP_D, TP_D);
    transpose_cast<<<dim3(TP_D4 / 32, TP_D / 32), dim3(32, 8), 0, stream>>>(mW, mWt, TP_D, TP_D4);
    transpose_cast<<<dim3(TP_D / 32, TP_D4 / 32), dim3(32, 8), 0, stream>>>(pW, pWt, TP_D4, TP_D);
    hipMemsetAsync(colsum, 0, (size_t)TP_LK * 4, stream);
    hipMemsetAsync(ctxF, 0, (size_t)TP_LQ * TP_D * 4, stream);

    // ---- QKV projections
    {
        GemmParams p{};
        p.A = memB; p.aZ = 0; p.lda = TP_D;
        p.Bt = qWt; p.bZ = 0; p.ldb = TP_D;
        p.M = TP_LQ; p.N = TP_D; p.K = TP_D;
        p.bias = qb; p.outB = Qf; p.ldc = TP_D; p.relu = 0;
        gemm_bf16<4><<<dim3(7, 13, 1), 256, 0, stream>>>(p);
    }
    {
        GemmParams p{};
        p.A = imgB; p.aZ = 0; p.lda = TP_D;
        p.Bt = kWt; p.bZ = 0; p.ldb = TP_D;
        p.M = TP_LK; p.N = TP_D; p.K = TP_D;
        p.bias = kb; p.outB = Kf; p.ldc = TP_D; p.relu = 0;
        gemm_bf16<4><<<dim3(7, 49, 1), 256, 0, stream>>>(p);
    }
    {
        GemmParams p{};
        p.A = imgB; p.aZ = 0; p.lda = TP_D;
        p.Bt = vWt; p.bZ = 0; p.ldb = TP_D;
        p.M = TP_LK; p.N = TP_D; p.K = TP_D;
        p.bias = vb; p.outB = Vf; p.ldc = TP_D; p.relu = 0;
        gemm_bf16<4><<<dim3(7, 49, 1), 256, 0, stream>>>(p);
    }
    transpose_bf16<<<dim3(TP_D / 32, TP_LK / 32, 1), dim3(32, 8), 0, stream>>>(Vf, Vtf, TP_LK, TP_D);

    // ---- attention
    const float scale = 0.09449111825230679f;  // 1/sqrt(112)
    for (int h0 = 0; h0 < TP_H; h0 += hc) {
        {
            GemmParams p{};
            p.A = Qf + h0 * TP_HD; p.aZ = TP_HD; p.lda = TP_D;
            p.Bt = Kf + h0 * TP_HD; p.bZ = TP_HD; p.ldb = TP_D;
            p.M = TP_LQ; p.N = TP_LK; p.K = TP_HD;
            p.outB = S; p.cZ = (long long)TP_LQ * TP_LK; p.ldc = TP_LK;
            p.scale = scale;
            gemm_bf16<1><<<dim3(49, 13, hc), 256, 0, stream>>>(p);
        }
        softmax_rows<<<hc * TP_LQ, 256, 0, stream>>>(S);
        colsum_kernel<<<dim3(7, 32), 256, 0, stream>>>(S, colsum, hc * TP_LQ);
        {
            GemmParams p{};
            p.A = S; p.aZ = (long long)TP_LQ * TP_LK; p.lda = TP_LK;
            p.Bt = Vtf; p.bZ = (long long)TP_HD * TP_LK; p.ldb = TP_LK;
            p.M = TP_LQ; p.N = TP_HD; p.K = PV_KC;
            p.outF = ctxF; p.hbase = h0;
            gemm_bf16<5><<<dim3(1, 13, hc * PV_KS), 256, 0, stream>>>(p);
        }
    }
    cast_f32_bf16<<<(TP_LQ * TP_D / 4 + 255) / 256, 256, 0, stream>>>(ctxF, ctxB, TP_LQ * TP_D);

    // ---- O-projection + residual (fp32) -> LN1
    {
        GemmParams p{};
        p.A = ctxB; p.aZ = 0; p.lda = TP_D;
        p.Bt = oWt; p.bZ = 0; p.ldb = TP_D;
        p.M = TP_LQ; p.N = TP_D; p.K = TP_D;
        p.bias = ob; p.res = mem; p.outF = pre1; p.ldc = TP_D;
        gemm_bf16<3><<<dim3(7, 13, 1), 256, 0, stream>>>(p);
    }
    layernorm_rows<<<TP_LQ, 256, 0, stream>>>(pre1, ln1g, ln1b, attn, attnB);

    // ---- MLP
    {
        GemmParams p{};
        p.A = attnB; p.aZ = 0; p.lda = TP_D;
        p.Bt = mWt; p.bZ = 0; p.ldb = TP_D;
        p.M = TP_LQ; p.N = TP_D4; p.K = TP_D;
        p.bias = mb; p.outB = hidden; p.ldc = TP_D4; p.relu = 1;
        gemm_bf16<4><<<dim3(28, 13, 1), 256, 0, stream>>>(p);
    }
    {
        GemmParams p{};
        p.A = hidden; p.aZ = 0; p.lda = TP_D4;
        p.Bt = pWt; p.bZ = 0; p.ldb = TP_D4;
        p.M = TP_LQ; p.N = TP_D; p.K = TP_D4;
        p.bias = pb; p.res = attn; p.outF = pre2; p.ldc = TP_D;
        gemm_bf16<3><<<dim3(7, 13, 1), 256, 0, stream>>>(p);
    }
    layernorm_rows<<<TP_LQ, 256, 0, stream>>>(pre2, ln2g, ln2b, out, nullptr);

    // ---- frame scores
    frame_scores_kernel<<<TP_F, 256, 0, stream>>>(colsum, out + (size_t)TP_LQ * TP_D);
}

// Round 3
// 635.768 us; speedup vs baseline: 1.3229x; 1.1837x over previous
//
#include <hip/hip_runtime.h>
#include <hip/hip_bf16.h>
#include <math.h>

#define TP_D   896
#define TP_H   8
#define TP_HD  112
#define TP_LQ  1568
#define TP_LK  6272
#define TP_D4  3584
#define TP_F   32
#define TP_P   196
#define PV_KS  7          // split-K factor for PV gemm (6272 = 7*896)
#define PV_KC  896

typedef unsigned short u16;
typedef float f32x4 __attribute__((ext_vector_type(4)));
typedef __bf16 bf16x8 __attribute__((ext_vector_type(8)));

__device__ inline float bf2f(u16 u) {
    return __uint_as_float(((unsigned int)u) << 16);
}
__device__ inline u16 f2bf(float f) {
    unsigned int x = __float_as_uint(f);
    unsigned int lsb = (x >> 16) & 1u;
    x += 0x7fffu + lsb;
    return (u16)(x >> 16);
}
__device__ inline ushort4 pack4(float a, float b, float c, float d) {
    return make_ushort4(f2bf(a), f2bf(b), f2bf(c), f2bf(d));
}

// ---------------------------------------------------------------- casts
__global__ void cast_f32_bf16(const float* __restrict__ src, u16* __restrict__ dst, int n) {
    int i = (blockIdx.x * blockDim.x + threadIdx.x) * 4;
    if (i + 3 < n) {
        float4 v = *(const float4*)(src + i);
        *(ushort4*)(dst + i) = pack4(v.x, v.y, v.z, v.w);
    } else {
        for (; i < n; ++i) dst[i] = f2bf(src[i]);
    }
}

// ctx fp32 (atomic-accumulated e*V) -> /l -> bf16
__global__ void cast_div_bf16(const float* __restrict__ src, const float* __restrict__ l,
                              u16* __restrict__ dst) {
    int i = (blockIdx.x * 256 + threadIdx.x) * 4;
    if (i >= TP_LQ * TP_D) return;
    int q = i / TP_D;
    int col = i - q * TP_D;
    int h = col / TP_HD;
    float inv = 1.f / l[h * TP_LQ + q];
    float4 v = *(const float4*)(src + i);
    *(ushort4*)(dst + i) = pack4(v.x * inv, v.y * inv, v.z * inv, v.w * inv);
}

// src fp32 [R][C] -> dst bf16 [C][R].  R,C multiples of 32. block (32,8)
__global__ void transpose_cast(const float* __restrict__ src, u16* __restrict__ dst, int R, int C) {
    __shared__ float t[32][33];
    int bx = blockIdx.x * 32;
    int by = blockIdx.y * 32;
    int tx = threadIdx.x, ty = threadIdx.y;
#pragma unroll
    for (int j = 0; j < 4; ++j)
        t[ty + j * 8][tx] = src[(size_t)(by + ty + j * 8) * C + bx + tx];
    __syncthreads();
#pragma unroll
    for (int j = 0; j < 4; ++j)
        dst[(size_t)(bx + ty + j * 8) * R + by + tx] = f2bf(t[tx][ty + j * 8]);
}

// ---------------------------------------------------------------- GEMM
// C[M,N] = A[M,K] @ Bt[N,K]^T, 128x128 tile, BK=32, mfma_f32_16x16x32_bf16.
// MODE 1: S-gemm. TRANSPOSED acc (lane holds 4 consecutive cols). Writes
//         e = exp(acc*scale) as ushort4; atomicAdd row-sums into outF.
// MODE 4: out bf16 = acc + bias[col] (relu optional)          (Q/K proj, MLP1)
// MODE 5: split-K PV: z -> (relhead, ks); atomicAdd fp32 into
//         outF[row*896 + (hbase+relhead)*112 + col], col < N
// MODE 6: generic split-K: z = k-slice (chunk p.kc); atomicAdd fp32 into
//         outF[row*ldc + col]  (bias/residual applied later in LN)
// MODE 7: V-proj writing V^T directly: out bf16 at outB[col*ldc + row],
//         normal acc (lane holds 4 consecutive rows) -> ushort4 along rows.
struct GemmParams {
    const u16* A;  long long aZ; int lda;
    const u16* Bt; long long bZ; int ldb;
    int M, N, K;
    const float* bias;
    float* outF;
    u16* outB; long long cZ; int ldc;
    float scale;
    int hbase;
    int relu;
    int kc;
};

#define LDS_STRIDE 56   // bf16 elems

template <int MODE>
__global__ __launch_bounds__(256, 2) void gemm_bf16(GemmParams p) {
    __shared__ u16 lsA[128 * LDS_STRIDE];
    __shared__ u16 lsB[128 * LDS_STRIDE];

    const int tid = threadIdx.x;
    const int z = blockIdx.z;
    const u16* A;
    const u16* Bt;
    int abshead = 0;
    if (MODE == 5) {
        const int rel = z / PV_KS;
        const int ks = z - rel * PV_KS;
        abshead = p.hbase + rel;
        A  = p.A  + (size_t)rel * p.aZ + (size_t)ks * PV_KC;
        Bt = p.Bt + (size_t)abshead * p.bZ + (size_t)ks * PV_KC;
    } else if (MODE == 6) {
        A  = p.A  + (size_t)z * p.kc;
        Bt = p.Bt + (size_t)z * p.kc;
    } else {
        A  = p.A  + (size_t)z * p.aZ;
        Bt = p.Bt + (size_t)z * p.bZ;
    }
    const int m0 = blockIdx.y * 128;
    const int n0 = blockIdx.x * 128;

    const int lane = tid & 63;
    const int w = tid >> 6;
    const int wm = (w >> 1) * 64, wn = (w & 1) * 64;
    const int c = lane & 15, q = lane >> 4;

    f32x4 acc[4][4];
#pragma unroll
    for (int i = 0; i < 4; ++i)
#pragma unroll
        for (int j = 0; j < 4; ++j) acc[i][j] = 0.f;

    const int r0 = tid >> 2;
    const int c8 = (tid & 3) * 8;
    int arow0 = m0 + r0;      if (arow0 >= p.M) arow0 = p.M - 1;
    int arow1 = m0 + r0 + 64; if (arow1 >= p.M) arow1 = p.M - 1;
    int brow0 = n0 + r0;      if (brow0 >= p.N) brow0 = p.N - 1;
    int brow1 = n0 + r0 + 64; if (brow1 >= p.N) brow1 = p.N - 1;
    const u16* a0 = A  + (size_t)arow0 * p.lda + c8;
    const u16* a1 = A  + (size_t)arow1 * p.lda + c8;
    const u16* b0 = Bt + (size_t)brow0 * p.ldb + c8;
    const u16* b1 = Bt + (size_t)brow1 * p.ldb + c8;

    const int KT = (p.K + 31) >> 5;
    for (int kt = 0; kt < KT; ++kt) {
        const int k0 = kt << 5;
        const bool valid = (k0 + c8 + 8) <= p.K;
        uint4 zv = make_uint4(0, 0, 0, 0);
        uint4 va0 = valid ? *(const uint4*)(a0 + k0) : zv;
        uint4 va1 = valid ? *(const uint4*)(a1 + k0) : zv;
        uint4 vb0 = valid ? *(const uint4*)(b0 + k0) : zv;
        uint4 vb1 = valid ? *(const uint4*)(b1 + k0) : zv;
        *(uint4*)(&lsA[r0 * LDS_STRIDE + c8])        = va0;
        *(uint4*)(&lsA[(r0 + 64) * LDS_STRIDE + c8]) = va1;
        *(uint4*)(&lsB[r0 * LDS_STRIDE + c8])        = vb0;
        *(uint4*)(&lsB[(r0 + 64) * LDS_STRIDE + c8]) = vb1;
        __syncthreads();

        bf16x8 af[4], bfv[4];
#pragma unroll
        for (int mi = 0; mi < 4; ++mi)
            af[mi] = *(const bf16x8*)(&lsA[(wm + mi * 16 + c) * LDS_STRIDE + q * 8]);
#pragma unroll
        for (int ni = 0; ni < 4; ++ni)
            bfv[ni] = *(const bf16x8*)(&lsB[(wn + ni * 16 + c) * LDS_STRIDE + q * 8]);
#pragma unroll
        for (int mi = 0; mi < 4; ++mi)
#pragma unroll
            for (int ni = 0; ni < 4; ++ni) {
                if (MODE == 1)   // transposed tile: lane regs = 4 consecutive cols
                    acc[mi][ni] = __builtin_amdgcn_mfma_f32_16x16x32_bf16(bfv[ni], af[mi], acc[mi][ni], 0, 0, 0);
                else
                    acc[mi][ni] = __builtin_amdgcn_mfma_f32_16x16x32_bf16(af[mi], bfv[ni], acc[mi][ni], 0, 0, 0);
            }
        __syncthreads();
    }

    if (MODE == 1) {
        // lane (c,q) tile (mi,ni) reg r -> S[m0+wm+mi*16+c][n0+wn+ni*16+q*4+r]
        u16* Sbase = p.outB + (size_t)z * p.cZ;
        float* lbase = p.outF + (size_t)z * TP_LQ;
#pragma unroll
        for (int mi = 0; mi < 4; ++mi) {
            const int srow = m0 + wm + mi * 16 + c;
            float rowpart = 0.f;
            if (srow < p.M) {
                u16* rp = Sbase + (size_t)srow * p.ldc;
#pragma unroll
                for (int ni = 0; ni < 4; ++ni) {
                    float e[4];
#pragma unroll
                    for (int r = 0; r < 4; ++r) {
                        float v = acc[mi][ni][r] * p.scale;
                        v = fminf(v, 30.f);
                        e[r] = __expf(v);
                        rowpart += e[r];
                    }
                    *(ushort4*)(rp + n0 + wn + ni * 16 + q * 4) = pack4(e[0], e[1], e[2], e[3]);
                }
            }
            rowpart += __shfl_xor(rowpart, 16, 64);
            rowpart += __shfl_xor(rowpart, 32, 64);
            if (q == 0 && srow < p.M) atomicAdd(lbase + srow, rowpart);
        }
        return;
    }

    if (MODE == 7) {
        // normal acc: lane regs = 4 consecutive rows -> contiguous along V^T inner dim
#pragma unroll
        for (int ni = 0; ni < 4; ++ni) {
            const int col = n0 + wn + ni * 16 + c;
            const float bv = p.bias[col];
#pragma unroll
            for (int mi = 0; mi < 4; ++mi) {
                const int mbase = m0 + wm + mi * 16 + q * 4;
                f32x4 a = acc[mi][ni];
                *(ushort4*)(p.outB + (size_t)col * p.ldc + mbase) =
                    pack4(a[0] + bv, a[1] + bv, a[2] + bv, a[3] + bv);
            }
        }
        return;
    }

    // epilogue (normal layout): col = lane&15, row = quad*4 + reg
#pragma unroll
    for (int mi = 0; mi < 4; ++mi) {
#pragma unroll
        for (int r = 0; r < 4; ++r) {
            const int row = m0 + wm + mi * 16 + q * 4 + r;
            if (row >= p.M) continue;
#pragma unroll
            for (int ni = 0; ni < 4; ++ni) {
                const int col = n0 + wn + ni * 16 + c;
                float v = acc[mi][ni][r];
                if (MODE == 4) {
                    v += p.bias[col];
                    if (p.relu) v = v > 0.f ? v : 0.f;
                    p.outB[(size_t)row * p.ldc + col] = f2bf(v);
                } else if (MODE == 5) {
                    if (col < p.N)
                        atomicAdd(&p.outF[(size_t)row * TP_D + abshead * TP_HD + col], v);
                } else if (MODE == 6) {
                    atomicAdd(&p.outF[(size_t)row * p.ldc + col], v);
                }
            }
        }
    }
}

// colsum[k] += sum over rows of e[row][k]/l[row]; vec4 columns per thread
__global__ void colsum_kernel(const u16* __restrict__ E, const float* __restrict__ l,
                              float* __restrict__ colsum, int nrows) {
    int c4 = blockIdx.x * 256 + threadIdx.x;   // vec4 col index
    if (c4 >= TP_LK / 4) return;
    int chunk = (nrows + gridDim.y - 1) / gridDim.y;
    int r0 = blockIdx.y * chunk;
    int r1 = r0 + chunk; if (r1 > nrows) r1 = nrows;
    float a0 = 0.f, a1 = 0.f, a2 = 0.f, a3 = 0.f;
    for (int r = r0; r < r1; ++r) {
        float inv = 1.f / l[r];
        ushort4 u = ((const ushort4*)(E + (size_t)r * TP_LK))[c4];
        a0 += bf2f(u.x) * inv; a1 += bf2f(u.y) * inv;
        a2 += bf2f(u.z) * inv; a3 += bf2f(u.w) * inv;
    }
    atomicAdd(&colsum[4 * c4 + 0], a0);
    atomicAdd(&colsum[4 * c4 + 1], a1);
    atomicAdd(&colsum[4 * c4 + 2], a2);
    atomicAdd(&colsum[4 * c4 + 3], a3);
}

// ---------------------------------------------------------------- layernorm
// t = x + bias + res; out = LN(t)*g + b
__global__ __launch_bounds__(256) void layernorm_rows(const float* __restrict__ x,
        const float* __restrict__ bias, const float* __restrict__ res,
        const float* __restrict__ g, const float* __restrict__ b,
        float* __restrict__ outF, u16* __restrict__ outB) {
    const int tid = threadIdx.x;
    const float* xr = x + (size_t)blockIdx.x * TP_D;
    const float* rr = res + (size_t)blockIdx.x * TP_D;
    float v[4];
#pragma unroll
    for (int i = 0; i < 4; ++i) {
        int idx = tid + i * 256;
        v[i] = (idx < TP_D) ? (xr[idx] + bias[idx] + rr[idx]) : 0.f;
    }
    float s = v[0] + v[1] + v[2] + v[3];
    __shared__ float red[4];
#pragma unroll
    for (int o = 32; o > 0; o >>= 1) s += __shfl_xor(s, o, 64);
    if ((tid & 63) == 0) red[tid >> 6] = s;
    __syncthreads();
    const float mu = (red[0] + red[1] + red[2] + red[3]) * (1.f / TP_D);
    __syncthreads();
    float ss = 0.f;
#pragma unroll
    for (int i = 0; i < 4; ++i) {
        int idx = tid + i * 256;
        if (idx < TP_D) { float d = v[i] - mu; ss += d * d; }
    }
#pragma unroll
    for (int o = 32; o > 0; o >>= 1) ss += __shfl_xor(ss, o, 64);
    if ((tid & 63) == 0) red[tid >> 6] = ss;
    __syncthreads();
    const float var = (red[0] + red[1] + red[2] + red[3]) * (1.f / TP_D);
    const float rs = rsqrtf(var + 1e-12f);
    float* of = outF + (size_t)blockIdx.x * TP_D;
    u16* obp = outB ? outB + (size_t)blockIdx.x * TP_D : nullptr;
#pragma unroll
    for (int i = 0; i < 4; ++i) {
        int idx = tid + i * 256;
        if (idx < TP_D) {
            float y = (v[i] - mu) * rs * g[idx] + b[idx];
            of[idx] = y;
            if (obp) obp[idx] = f2bf(y);
        }
    }
}

__global__ void frame_scores_kernel(const float* __restrict__ colsum, float* __restrict__ out) {
    const int tid = threadIdx.x;
    float v = (tid < TP_P) ? colsum[blockIdx.x * TP_P + tid] : 0.f;
    __shared__ float red[4];
#pragma unroll
    for (int o = 32; o > 0; o >>= 1) v += __shfl_xor(v, o, 64);
    if ((tid & 63) == 0) red[tid >> 6] = v;
    __syncthreads();
    if (tid == 0) out[blockIdx.x] = (red[0] + red[1] + red[2] + red[3]) * (1.f / TP_P);
}

// ---------------------------------------------------------------- launch
extern "C" void kernel_launch(void* const* d_in, const int* in_sizes, int n_in,
                              void* d_out, int out_size, void* d_ws, size_t ws_size,
                              hipStream_t stream) {
    const float* img  = (const float*)d_in[0];
    const float* mem  = (const float*)d_in[1];
    const float* qW   = (const float*)d_in[2];
    const float* qb   = (const float*)d_in[3];
    const float* kW   = (const float*)d_in[4];
    const float* kb   = (const float*)d_in[5];
    const float* vW   = (const float*)d_in[6];
    const float* vb   = (const float*)d_in[7];
    const float* oW   = (const float*)d_in[8];
    const float* ob   = (const float*)d_in[9];
    const float* ln1g = (const float*)d_in[10];
    const float* ln1b = (const float*)d_in[11];
    const float* mW   = (const float*)d_in[12];
    const float* mb   = (const float*)d_in[13];
    const float* pW   = (const float*)d_in[14];
    const float* pb   = (const float*)d_in[15];
    const float* ln2g = (const float*)d_in[16];
    const float* ln2b = (const float*)d_in[17];
    float* out = (float*)d_out;

    char* base = (char*)d_ws;
    size_t off = 0;
    auto take = [&](size_t nbytes) -> void* {
        void* p = base + off;
        off += (nbytes + 255) & ~(size_t)255;
        return p;
    };

    u16* imgB  = (u16*)take((size_t)TP_LK * TP_D * 2);
    u16* memB  = (u16*)take((size_t)TP_LQ * TP_D * 2);
    u16* qWt   = (u16*)take((size_t)TP_D * TP_D * 2);
    u16* kWt   = (u16*)take((size_t)TP_D * TP_D * 2);
    u16* vWt   = (u16*)take((size_t)TP_D * TP_D * 2);
    u16* oWt   = (u16*)take((size_t)TP_D * TP_D * 2);
    u16* mWt   = (u16*)take((size_t)TP_D * TP_D4 * 2);
    u16* pWt   = (u16*)take((size_t)TP_D * TP_D4 * 2);
    u16* Qf    = (u16*)take((size_t)TP_LQ * TP_D * 2);
    u16* Kf    = (u16*)take((size_t)TP_LK * TP_D * 2);
    u16* Vtf   = (u16*)take((size_t)TP_LK * TP_D * 2);
    float* ctxF  = (float*)take((size_t)TP_LQ * TP_D * 4);
    u16* ctxB  = (u16*)take((size_t)TP_LQ * TP_D * 2);
    float* pre1  = (float*)take((size_t)TP_LQ * TP_D * 4);
    float* attn  = (float*)take((size_t)TP_LQ * TP_D * 4);
    u16* attnB = (u16*)take((size_t)TP_LQ * TP_D * 2);
    u16* hidden= (u16*)take((size_t)TP_LQ * TP_D4 * 2);
    float* pre2  = (float*)take((size_t)TP_LQ * TP_D * 4);
    float* colsum= (float*)take((size_t)TP_LK * 4);
    float* lsum  = (float*)take((size_t)TP_H * TP_LQ * 4);

    const size_t perHeadS = (size_t)TP_LQ * TP_LK;
    const int hc = (ws_size >= off + 8 * perHeadS * 2 + 4096) ? 8 : 1;
    u16* S = (u16*)take((size_t)hc * perHeadS * 2);

    // ---- casts / transposes / zero-init
    cast_f32_bf16<<<(TP_LK * TP_D / 4 + 255) / 256, 256, 0, stream>>>(img, imgB, TP_LK * TP_D);
    cast_f32_bf16<<<(TP_LQ * TP_D / 4 + 255) / 256, 256, 0, stream>>>(mem, memB, TP_LQ * TP_D);
    transpose_cast<<<dim3(28, 28), dim3(32, 8), 0, stream>>>(qW, qWt, TP_D, TP_D);
    transpose_cast<<<dim3(28, 28), dim3(32, 8), 0, stream>>>(kW, kWt, TP_D, TP_D);
    transpose_cast<<<dim3(28, 28), dim3(32, 8), 0, stream>>>(vW, vWt, TP_D, TP_D);
    transpose_cast<<<dim3(28, 28), dim3(32, 8), 0, stream>>>(oW, oWt, TP_D, TP_D);
    transpose_cast<<<dim3(TP_D4 / 32, TP_D / 32), dim3(32, 8), 0, stream>>>(mW, mWt, TP_D, TP_D4);
    transpose_cast<<<dim3(TP_D / 32, TP_D4 / 32), dim3(32, 8), 0, stream>>>(pW, pWt, TP_D4, TP_D);
    hipMemsetAsync(colsum, 0, (size_t)TP_LK * 4, stream);
    hipMemsetAsync(lsum, 0, (size_t)TP_H * TP_LQ * 4, stream);
    hipMemsetAsync(ctxF, 0, (size_t)TP_LQ * TP_D * 4, stream);
    hipMemsetAsync(pre1, 0, (size_t)TP_LQ * TP_D * 4, stream);
    hipMemsetAsync(pre2, 0, (size_t)TP_LQ * TP_D * 4, stream);

    // ---- QKV projections
    {
        GemmParams p{};
        p.A = memB; p.aZ = 0; p.lda = TP_D;
        p.Bt = qWt; p.bZ = 0; p.ldb = TP_D;
        p.M = TP_LQ; p.N = TP_D; p.K = TP_D;
        p.bias = qb; p.outB = Qf; p.ldc = TP_D; p.relu = 0;
        gemm_bf16<4><<<dim3(7, 13, 1), 256, 0, stream>>>(p);
    }
    {
        GemmParams p{};
        p.A = imgB; p.aZ = 0; p.lda = TP_D;
        p.Bt = kWt; p.bZ = 0; p.ldb = TP_D;
        p.M = TP_LK; p.N = TP_D; p.K = TP_D;
        p.bias = kb; p.outB = Kf; p.ldc = TP_D; p.relu = 0;
        gemm_bf16<4><<<dim3(7, 49, 1), 256, 0, stream>>>(p);
    }
    {   // V-projection writing V^T [896][6272] directly
        GemmParams p{};
        p.A = imgB; p.aZ = 0; p.lda = TP_D;
        p.Bt = vWt; p.bZ = 0; p.ldb = TP_D;
        p.M = TP_LK; p.N = TP_D; p.K = TP_D;
        p.bias = vb; p.outB = Vtf; p.ldc = TP_LK;
        gemm_bf16<7><<<dim3(7, 49, 1), 256, 0, stream>>>(p);
    }

    // ---- attention (no-max softmax: e = exp(s), row-sums l via atomics)
    const float scale = 0.09449111825230679f;  // 1/sqrt(112)
    for (int h0 = 0; h0 < TP_H; h0 += hc) {
        {
            GemmParams p{};
            p.A = Qf + h0 * TP_HD; p.aZ = TP_HD; p.lda = TP_D;
            p.Bt = Kf + h0 * TP_HD; p.bZ = TP_HD; p.ldb = TP_D;
            p.M = TP_LQ; p.N = TP_LK; p.K = TP_HD;
            p.outB = S; p.cZ = (long long)TP_LQ * TP_LK; p.ldc = TP_LK;
            p.outF = lsum + (size_t)h0 * TP_LQ;
            p.scale = scale;
            gemm_bf16<1><<<dim3(49, 13, hc), 256, 0, stream>>>(p);
        }
        colsum_kernel<<<dim3(7, 32), 256, 0, stream>>>(S, lsum + (size_t)h0 * TP_LQ, colsum, hc * TP_LQ);
        {
            GemmParams p{};
            p.A = S; p.aZ = (long long)TP_LQ * TP_LK; p.lda = TP_LK;
            p.Bt = Vtf; p.bZ = (long long)TP_HD * TP_LK; p.ldb = TP_LK;
            p.M = TP_LQ; p.N = TP_HD; p.K = PV_KC;
            p.outF = ctxF; p.hbase = h0;
            gemm_bf16<5><<<dim3(1, 13, hc * PV_KS), 256, 0, stream>>>(p);
        }
    }
    cast_div_bf16<<<(TP_LQ * TP_D / 4 + 255) / 256, 256, 0, stream>>>(ctxF, lsum, ctxB);

    // ---- O-projection split-K x2 -> pre1 (bias+residual in LN1)
    {
        GemmParams p{};
        p.A = ctxB; p.lda = TP_D;
        p.Bt = oWt; p.ldb = TP_D;
        p.M = TP_LQ; p.N = TP_D; p.K = 448; p.kc = 448;
        p.outF = pre1; p.ldc = TP_D;
        gemm_bf16<6><<<dim3(7, 13, 2), 256, 0, stream>>>(p);
    }
    layernorm_rows<<<TP_LQ, 256, 0, stream>>>(pre1, ob, mem, ln1g, ln1b, attn, attnB);

    // ---- MLP
    {
        GemmParams p{};
        p.A = attnB; p.aZ = 0; p.lda = TP_D;
        p.Bt = mWt; p.bZ = 0; p.ldb = TP_D;
        p.M = TP_LQ; p.N = TP_D4; p.K = TP_D;
        p.bias = mb; p.outB = hidden; p.ldc = TP_D4; p.relu = 1;
        gemm_bf16<4><<<dim3(28, 13, 1), 256, 0, stream>>>(p);
    }
    {   // MLP2 split-K x4 -> pre2 (bias+residual in LN2)
        GemmParams p{};
        p.A = hidden; p.lda = TP_D4;
        p.Bt = pWt; p.ldb = TP_D4;
        p.M = TP_LQ; p.N = TP_D; p.K = 896; p.kc = 896;
        p.outF = pre2; p.ldc = TP_D;
        gemm_bf16<6><<<dim3(7, 13, 4), 256, 0, stream>>>(p);
    }
    layernorm_rows<<<TP_LQ, 256, 0, stream>>>(pre2, pb, attn, ln2g, ln2b, out, nullptr);

    // ---- frame scores
    frame_scores_kernel<<<TP_F, 256, 0, stream>>>(colsum, out + (size_t)TP_LQ * TP_D);
}

// Round 4
// 557.920 us; speedup vs baseline: 1.5075x; 1.1395x over previous
//
#include <hip/hip_runtime.h>
#include <hip/hip_bf16.h>
#include <math.h>

#define TP_D   896
#define TP_H   8
#define TP_HD  112
#define TP_LQ  1568
#define TP_LK  6272
#define TP_D4  3584
#define TP_F   32
#define TP_P   196

typedef unsigned short u16;
typedef float f32x4 __attribute__((ext_vector_type(4)));
typedef __bf16 bf16x8 __attribute__((ext_vector_type(8)));

__device__ inline float bf2f(u16 u) {
    return __uint_as_float(((unsigned int)u) << 16);
}
__device__ inline u16 f2bf(float f) {
    unsigned int x = __float_as_uint(f);
    unsigned int lsb = (x >> 16) & 1u;
    x += 0x7fffu + lsb;
    return (u16)(x >> 16);
}
__device__ inline ushort4 pack4(float a, float b, float c, float d) {
    return make_ushort4(f2bf(a), f2bf(b), f2bf(c), f2bf(d));
}
// XOR-swizzled 128-col LDS tile index (16B-block swizzle, 2-way max conflict)
__device__ inline int pidx(int row, int col) {
    return row * 128 + (col ^ ((row & 7) << 3));
}

// ---------------------------------------------------------------- casts
__global__ void cast_f32_bf16(const float* __restrict__ src, u16* __restrict__ dst, int n) {
    int i = (blockIdx.x * blockDim.x + threadIdx.x) * 4;
    if (i + 3 < n) {
        float4 v = *(const float4*)(src + i);
        *(ushort4*)(dst + i) = pack4(v.x, v.y, v.z, v.w);
    } else {
        for (; i < n; ++i) dst[i] = f2bf(src[i]);
    }
}

// ctx fp32 (atomic-accumulated e*V) -> /l -> bf16
__global__ void cast_div_bf16(const float* __restrict__ src, const float* __restrict__ l,
                              u16* __restrict__ dst) {
    int i = (blockIdx.x * 256 + threadIdx.x) * 4;
    if (i >= TP_LQ * TP_D) return;
    int q = i / TP_D;
    int col = i - q * TP_D;
    int h = col / TP_HD;
    float inv = 1.f / l[h * TP_LQ + q];
    float4 v = *(const float4*)(src + i);
    *(ushort4*)(dst + i) = pack4(v.x * inv, v.y * inv, v.z * inv, v.w * inv);
}

// src fp32 [R][C] -> dst bf16 [C][R].  R,C multiples of 32. block (32,8)
__global__ void transpose_cast(const float* __restrict__ src, u16* __restrict__ dst, int R, int C) {
    __shared__ float t[32][33];
    int bx = blockIdx.x * 32;
    int by = blockIdx.y * 32;
    int tx = threadIdx.x, ty = threadIdx.y;
#pragma unroll
    for (int j = 0; j < 4; ++j)
        t[ty + j * 8][tx] = src[(size_t)(by + ty + j * 8) * C + bx + tx];
    __syncthreads();
#pragma unroll
    for (int j = 0; j < 4; ++j)
        dst[(size_t)(bx + ty + j * 8) * R + by + tx] = f2bf(t[tx][ty + j * 8]);
}

// ---------------------------------------------------------------- GEMM
// C[M,N] = A[M,K] @ Bt[N,K]^T, 128x128 tile, BK=32, mfma_f32_16x16x32_bf16.
// MODE 4: out bf16 = acc + bias[col] (relu optional)          (Q/K proj, MLP1)
// MODE 6: generic split-K: z = k-slice (chunk p.kc); atomicAdd fp32 into
//         outF[row*ldc + col]  (bias/residual applied later in LN)
// MODE 7: V-proj writing V^T directly: out bf16 at outB[col*ldc + row]
struct GemmParams {
    const u16* A;  long long aZ; int lda;
    const u16* Bt; long long bZ; int ldb;
    int M, N, K;
    const float* bias;
    float* outF;
    u16* outB; long long cZ; int ldc;
    float scale;
    int hbase;
    int relu;
    int kc;
};

#define LDS_STRIDE 56   // bf16 elems

template <int MODE>
__global__ __launch_bounds__(256, 2) void gemm_bf16(GemmParams p) {
    __shared__ u16 lsA[128 * LDS_STRIDE];
    __shared__ u16 lsB[128 * LDS_STRIDE];

    const int tid = threadIdx.x;
    const int z = blockIdx.z;
    const u16* A;
    const u16* Bt;
    if (MODE == 6) {
        A  = p.A  + (size_t)z * p.kc;
        Bt = p.Bt + (size_t)z * p.kc;
    } else {
        A  = p.A  + (size_t)z * p.aZ;
        Bt = p.Bt + (size_t)z * p.bZ;
    }
    const int m0 = blockIdx.y * 128;
    const int n0 = blockIdx.x * 128;

    const int lane = tid & 63;
    const int w = tid >> 6;
    const int wm = (w >> 1) * 64, wn = (w & 1) * 64;
    const int c = lane & 15, q = lane >> 4;

    f32x4 acc[4][4];
#pragma unroll
    for (int i = 0; i < 4; ++i)
#pragma unroll
        for (int j = 0; j < 4; ++j) acc[i][j] = 0.f;

    const int r0 = tid >> 2;
    const int c8 = (tid & 3) * 8;
    int arow0 = m0 + r0;      if (arow0 >= p.M) arow0 = p.M - 1;
    int arow1 = m0 + r0 + 64; if (arow1 >= p.M) arow1 = p.M - 1;
    int brow0 = n0 + r0;      if (brow0 >= p.N) brow0 = p.N - 1;
    int brow1 = n0 + r0 + 64; if (brow1 >= p.N) brow1 = p.N - 1;
    const u16* a0 = A  + (size_t)arow0 * p.lda + c8;
    const u16* a1 = A  + (size_t)arow1 * p.lda + c8;
    const u16* b0 = Bt + (size_t)brow0 * p.ldb + c8;
    const u16* b1 = Bt + (size_t)brow1 * p.ldb + c8;

    const int KT = (p.K + 31) >> 5;
    for (int kt = 0; kt < KT; ++kt) {
        const int k0 = kt << 5;
        const bool valid = (k0 + c8 + 8) <= p.K;
        uint4 zv = make_uint4(0, 0, 0, 0);
        uint4 va0 = valid ? *(const uint4*)(a0 + k0) : zv;
        uint4 va1 = valid ? *(const uint4*)(a1 + k0) : zv;
        uint4 vb0 = valid ? *(const uint4*)(b0 + k0) : zv;
        uint4 vb1 = valid ? *(const uint4*)(b1 + k0) : zv;
        *(uint4*)(&lsA[r0 * LDS_STRIDE + c8])        = va0;
        *(uint4*)(&lsA[(r0 + 64) * LDS_STRIDE + c8]) = va1;
        *(uint4*)(&lsB[r0 * LDS_STRIDE + c8])        = vb0;
        *(uint4*)(&lsB[(r0 + 64) * LDS_STRIDE + c8]) = vb1;
        __syncthreads();

        bf16x8 af[4], bfv[4];
#pragma unroll
        for (int mi = 0; mi < 4; ++mi)
            af[mi] = *(const bf16x8*)(&lsA[(wm + mi * 16 + c) * LDS_STRIDE + q * 8]);
#pragma unroll
        for (int ni = 0; ni < 4; ++ni)
            bfv[ni] = *(const bf16x8*)(&lsB[(wn + ni * 16 + c) * LDS_STRIDE + q * 8]);
#pragma unroll
        for (int mi = 0; mi < 4; ++mi)
#pragma unroll
            for (int ni = 0; ni < 4; ++ni)
                acc[mi][ni] = __builtin_amdgcn_mfma_f32_16x16x32_bf16(af[mi], bfv[ni], acc[mi][ni], 0, 0, 0);
        __syncthreads();
    }

    if (MODE == 7) {
        // lane regs = 4 consecutive rows -> contiguous along V^T inner dim
#pragma unroll
        for (int ni = 0; ni < 4; ++ni) {
            const int col = n0 + wn + ni * 16 + c;
            const float bv = p.bias[col];
#pragma unroll
            for (int mi = 0; mi < 4; ++mi) {
                const int mbase = m0 + wm + mi * 16 + q * 4;
                f32x4 a = acc[mi][ni];
                *(ushort4*)(p.outB + (size_t)col * p.ldc + mbase) =
                    pack4(a[0] + bv, a[1] + bv, a[2] + bv, a[3] + bv);
            }
        }
        return;
    }

#pragma unroll
    for (int mi = 0; mi < 4; ++mi) {
#pragma unroll
        for (int r = 0; r < 4; ++r) {
            const int row = m0 + wm + mi * 16 + q * 4 + r;
            if (row >= p.M) continue;
#pragma unroll
            for (int ni = 0; ni < 4; ++ni) {
                const int col = n0 + wn + ni * 16 + c;
                float v = acc[mi][ni][r];
                if (MODE == 4) {
                    v += p.bias[col];
                    if (p.relu) v = v > 0.f ? v : 0.f;
                    p.outB[(size_t)row * p.ldc + col] = f2bf(v);
                } else if (MODE == 6) {
                    atomicAdd(&p.outF[(size_t)row * p.ldc + col], v);
                }
            }
        }
    }
}

// ---------------------------------------------------------------- fused attention
// grid (7 k-chunks, 13 q-tiles, 8 heads).  Per block: for each of 7 key-blocks
// (128 keys): S-tile = Q K^T (transposed acc), e = exp(s*scale) -> global E +
// LDS lsP + reg row-sums; then PV MFMAs (P from lsP, V^T tiles from Vtf) into
// reg ctx accumulator. Epilogue: atomicAdd l and ctxF.
__global__ __launch_bounds__(256, 2) void attn_fused(
        const u16* __restrict__ Qf, const u16* __restrict__ Kf,
        const u16* __restrict__ Vtf, u16* __restrict__ E,
        float* __restrict__ lsum, float* __restrict__ ctxF, float scale) {
    __shared__ u16 lsQ[128 * 128];   // swizzled, cols 112..127 zero
    __shared__ u16 lsB[128 * 40];    // K-tile or V-tile staging (32 cols)
    __shared__ u16 lsP[128 * 128];   // swizzled e tile

    const int ks  = blockIdx.x;         // key chunk 0..6 (896 keys each)
    const int m0  = blockIdx.y * 128;   // query tile
    const int h   = blockIdx.z;
    const int tid = threadIdx.x;
    const int lane = tid & 63, w = tid >> 6;
    const int wm = (w >> 1) * 64, wn = (w & 1) * 64;
    const int c = lane & 15, q = lane >> 4;

    // ---- stage Q tile once (128 rows x 128 cols, 112 valid, zero-padded)
    {
        const int row = tid >> 1;
        const int half = (tid & 1) * 64;
        int qrow = m0 + row; if (qrow > TP_LQ - 1) qrow = TP_LQ - 1;
        const u16* src = Qf + (size_t)qrow * TP_D + h * TP_HD;
#pragma unroll
        for (int j = 0; j < 8; ++j) {
            int col = half + j * 8;
            uint4 v = make_uint4(0, 0, 0, 0);
            if (col + 8 <= TP_HD) v = *(const uint4*)(src + col);
            *(uint4*)(&lsQ[pidx(row, col)]) = v;
        }
    }

    const int r0 = tid >> 2;
    const int c8 = (tid & 3) * 8;
    const int keybase = ks * 896;

    f32x4 acc_pv[4][4];
#pragma unroll
    for (int i = 0; i < 4; ++i)
#pragma unroll
        for (int j = 0; j < 4; ++j) acc_pv[i][j] = 0.f;
    float rs[4] = {0.f, 0.f, 0.f, 0.f};

    for (int kb = 0; kb < 7; ++kb) {
        const int kblk = keybase + kb * 128;
        f32x4 acc_s[4][4];
#pragma unroll
        for (int i = 0; i < 4; ++i)
#pragma unroll
            for (int j = 0; j < 4; ++j) acc_s[i][j] = 0.f;

        // ---- S phase: 4 kt over head dim (112, zero-padded to 128)
#pragma unroll
        for (int kt = 0; kt < 4; ++kt) {
            const int k0 = kt * 32;
            const bool valid = (k0 + c8 + 8) <= TP_HD;
            uint4 zv = make_uint4(0, 0, 0, 0);
            uint4 vb0 = valid ? *(const uint4*)(Kf + (size_t)(kblk + r0) * TP_D + h * TP_HD + k0 + c8) : zv;
            uint4 vb1 = valid ? *(const uint4*)(Kf + (size_t)(kblk + r0 + 64) * TP_D + h * TP_HD + k0 + c8) : zv;
            __syncthreads();   // protect lsB from previous consumer
            *(uint4*)(&lsB[r0 * 40 + c8])        = vb0;
            *(uint4*)(&lsB[(r0 + 64) * 40 + c8]) = vb1;
            __syncthreads();
            bf16x8 af[4], bfv[4];
#pragma unroll
            for (int mi = 0; mi < 4; ++mi)
                af[mi] = *(const bf16x8*)(&lsQ[pidx(wm + mi * 16 + c, k0 + q * 8)]);
#pragma unroll
            for (int ni = 0; ni < 4; ++ni)
                bfv[ni] = *(const bf16x8*)(&lsB[(wn + ni * 16 + c) * 40 + q * 8]);
#pragma unroll
            for (int mi = 0; mi < 4; ++mi)
#pragma unroll
                for (int ni = 0; ni < 4; ++ni)
                    acc_s[mi][ni] = __builtin_amdgcn_mfma_f32_16x16x32_bf16(bfv[ni], af[mi], acc_s[mi][ni], 0, 0, 0);
        }

        // ---- epilogue: e = exp(s*scale); store E + lsP; reg row-sums
        __syncthreads();   // previous PV reads of lsP complete
#pragma unroll
        for (int mi = 0; mi < 4; ++mi) {
            const int prow = wm + mi * 16 + c;       // query row in tile
            const int qr = m0 + prow;
            const bool qv = qr < TP_LQ;
            float rp = 0.f;
#pragma unroll
            for (int ni = 0; ni < 4; ++ni) {
                float e0, e1, e2, e3;
                {
                    f32x4 a = acc_s[mi][ni];
                    e0 = __expf(fminf(a[0] * scale, 30.f));
                    e1 = __expf(fminf(a[1] * scale, 30.f));
                    e2 = __expf(fminf(a[2] * scale, 30.f));
                    e3 = __expf(fminf(a[3] * scale, 30.f));
                }
                rp += (e0 + e1) + (e2 + e3);
                ushort4 pk = pack4(e0, e1, e2, e3);
                const int kcol = wn + ni * 16 + q * 4;
                if (qv)
                    *(ushort4*)(E + ((size_t)h * TP_LQ + qr) * TP_LK + kblk + kcol) = pk;
                *(ushort4*)(&lsP[pidx(prow, kcol)]) = pk;
            }
            rs[mi] += rp;
        }

        // ---- PV phase: 4 kt over the 128 keys of this block
#pragma unroll
        for (int kt = 0; kt < 4; ++kt) {
            const int kk = kblk + kt * 32 + c8;
            int d0 = r0;                               // < 112 always
            int d1 = r0 + 64; if (d1 > TP_HD - 1) d1 = TP_HD - 1;
            uint4 vb0 = *(const uint4*)(Vtf + ((size_t)h * TP_HD + d0) * TP_LK + kk);
            uint4 vb1 = *(const uint4*)(Vtf + ((size_t)h * TP_HD + d1) * TP_LK + kk);
            __syncthreads();   // lsB reuse; first iter: lsP writes visible
            *(uint4*)(&lsB[r0 * 40 + c8])        = vb0;
            *(uint4*)(&lsB[(r0 + 64) * 40 + c8]) = vb1;
            __syncthreads();
            bf16x8 ap[4], bv[4];
#pragma unroll
            for (int mi = 0; mi < 4; ++mi)
                ap[mi] = *(const bf16x8*)(&lsP[pidx(wm + mi * 16 + c, kt * 32 + q * 8)]);
#pragma unroll
            for (int ni = 0; ni < 4; ++ni)
                bv[ni] = *(const bf16x8*)(&lsB[(wn + ni * 16 + c) * 40 + q * 8]);
#pragma unroll
            for (int mi = 0; mi < 4; ++mi)
#pragma unroll
                for (int ni = 0; ni < 4; ++ni)
                    acc_pv[mi][ni] = __builtin_amdgcn_mfma_f32_16x16x32_bf16(ap[mi], bv[ni], acc_pv[mi][ni], 0, 0, 0);
        }
    }

    // ---- row-sum atomics (l)
#pragma unroll
    for (int mi = 0; mi < 4; ++mi) {
        float rp = rs[mi];
        rp += __shfl_xor(rp, 16, 64);
        rp += __shfl_xor(rp, 32, 64);
        const int qr = m0 + wm + mi * 16 + c;
        if (q == 0 && qr < TP_LQ) atomicAdd(&lsum[h * TP_LQ + qr], rp);
    }
    // ---- ctx atomics (normal C/D layout: col=d, rows q*4+r)
#pragma unroll
    for (int mi = 0; mi < 4; ++mi) {
#pragma unroll
        for (int r = 0; r < 4; ++r) {
            const int qr = m0 + wm + mi * 16 + q * 4 + r;
            if (qr >= TP_LQ) continue;
#pragma unroll
            for (int ni = 0; ni < 4; ++ni) {
                const int d = wn + ni * 16 + c;
                if (d < TP_HD)
                    atomicAdd(&ctxF[(size_t)qr * TP_D + h * TP_HD + d], acc_pv[mi][ni][r]);
            }
        }
    }
}

// colsum[k] += sum over rows of e[row][k]/l[row]; vec4 columns per thread
__global__ void colsum_kernel(const u16* __restrict__ E, const float* __restrict__ l,
                              float* __restrict__ colsum, int nrows) {
    int c4 = blockIdx.x * 256 + threadIdx.x;   // vec4 col index
    if (c4 >= TP_LK / 4) return;
    int chunk = (nrows + gridDim.y - 1) / gridDim.y;
    int r0 = blockIdx.y * chunk;
    int r1 = r0 + chunk; if (r1 > nrows) r1 = nrows;
    float a0 = 0.f, a1 = 0.f, a2 = 0.f, a3 = 0.f;
    for (int r = r0; r < r1; ++r) {
        float inv = 1.f / l[r];
        ushort4 u = ((const ushort4*)(E + (size_t)r * TP_LK))[c4];
        a0 += bf2f(u.x) * inv; a1 += bf2f(u.y) * inv;
        a2 += bf2f(u.z) * inv; a3 += bf2f(u.w) * inv;
    }
    atomicAdd(&colsum[4 * c4 + 0], a0);
    atomicAdd(&colsum[4 * c4 + 1], a1);
    atomicAdd(&colsum[4 * c4 + 2], a2);
    atomicAdd(&colsum[4 * c4 + 3], a3);
}

// ---------------------------------------------------------------- layernorm
// t = x + bias + res; out = LN(t)*g + b
__global__ __launch_bounds__(256) void layernorm_rows(const float* __restrict__ x,
        const float* __restrict__ bias, const float* __restrict__ res,
        const float* __restrict__ g, const float* __restrict__ b,
        float* __restrict__ outF, u16* __restrict__ outB) {
    const int tid = threadIdx.x;
    const float* xr = x + (size_t)blockIdx.x * TP_D;
    const float* rr = res + (size_t)blockIdx.x * TP_D;
    float v[4];
#pragma unroll
    for (int i = 0; i < 4; ++i) {
        int idx = tid + i * 256;
        v[i] = (idx < TP_D) ? (xr[idx] + bias[idx] + rr[idx]) : 0.f;
    }
    float s = v[0] + v[1] + v[2] + v[3];
    __shared__ float red[4];
#pragma unroll
    for (int o = 32; o > 0; o >>= 1) s += __shfl_xor(s, o, 64);
    if ((tid & 63) == 0) red[tid >> 6] = s;
    __syncthreads();
    const float mu = (red[0] + red[1] + red[2] + red[3]) * (1.f / TP_D);
    __syncthreads();
    float ss = 0.f;
#pragma unroll
    for (int i = 0; i < 4; ++i) {
        int idx = tid + i * 256;
        if (idx < TP_D) { float d = v[i] - mu; ss += d * d; }
    }
#pragma unroll
    for (int o = 32; o > 0; o >>= 1) ss += __shfl_xor(ss, o, 64);
    if ((tid & 63) == 0) red[tid >> 6] = ss;
    __syncthreads();
    const float var = (red[0] + red[1] + red[2] + red[3]) * (1.f / TP_D);
    const float rs = rsqrtf(var + 1e-12f);
    float* of = outF + (size_t)blockIdx.x * TP_D;
    u16* obp = outB ? outB + (size_t)blockIdx.x * TP_D : nullptr;
#pragma unroll
    for (int i = 0; i < 4; ++i) {
        int idx = tid + i * 256;
        if (idx < TP_D) {
            float y = (v[i] - mu) * rs * g[idx] + b[idx];
            of[idx] = y;
            if (obp) obp[idx] = f2bf(y);
        }
    }
}

__global__ void frame_scores_kernel(const float* __restrict__ colsum, float* __restrict__ out) {
    const int tid = threadIdx.x;
    float v = (tid < TP_P) ? colsum[blockIdx.x * TP_P + tid] : 0.f;
    __shared__ float red[4];
#pragma unroll
    for (int o = 32; o > 0; o >>= 1) v += __shfl_xor(v, o, 64);
    if ((tid & 63) == 0) red[tid >> 6] = v;
    __syncthreads();
    if (tid == 0) out[blockIdx.x] = (red[0] + red[1] + red[2] + red[3]) * (1.f / TP_P);
}

// ---------------------------------------------------------------- launch
extern "C" void kernel_launch(void* const* d_in, const int* in_sizes, int n_in,
                              void* d_out, int out_size, void* d_ws, size_t ws_size,
                              hipStream_t stream) {
    const float* img  = (const float*)d_in[0];
    const float* mem  = (const float*)d_in[1];
    const float* qW   = (const float*)d_in[2];
    const float* qb   = (const float*)d_in[3];
    const float* kW   = (const float*)d_in[4];
    const float* kb   = (const float*)d_in[5];
    const float* vW   = (const float*)d_in[6];
    const float* vb   = (const float*)d_in[7];
    const float* oW   = (const float*)d_in[8];
    const float* ob   = (const float*)d_in[9];
    const float* ln1g = (const float*)d_in[10];
    const float* ln1b = (const float*)d_in[11];
    const float* mW   = (const float*)d_in[12];
    const float* mb   = (const float*)d_in[13];
    const float* pW   = (const float*)d_in[14];
    const float* pb   = (const float*)d_in[15];
    const float* ln2g = (const float*)d_in[16];
    const float* ln2b = (const float*)d_in[17];
    float* out = (float*)d_out;

    char* base = (char*)d_ws;
    size_t off = 0;
    auto take = [&](size_t nbytes) -> void* {
        void* p = base + off;
        off += (nbytes + 255) & ~(size_t)255;
        return p;
    };

    u16* imgB  = (u16*)take((size_t)TP_LK * TP_D * 2);
    u16* memB  = (u16*)take((size_t)TP_LQ * TP_D * 2);
    u16* qWt   = (u16*)take((size_t)TP_D * TP_D * 2);
    u16* kWt   = (u16*)take((size_t)TP_D * TP_D * 2);
    u16* vWt   = (u16*)take((size_t)TP_D * TP_D * 2);
    u16* oWt   = (u16*)take((size_t)TP_D * TP_D * 2);
    u16* mWt   = (u16*)take((size_t)TP_D * TP_D4 * 2);
    u16* pWt   = (u16*)take((size_t)TP_D * TP_D4 * 2);
    u16* Qf    = (u16*)take((size_t)TP_LQ * TP_D * 2);
    u16* Kf    = (u16*)take((size_t)TP_LK * TP_D * 2);
    u16* Vtf   = (u16*)take((size_t)TP_LK * TP_D * 2);
    float* ctxF  = (float*)take((size_t)TP_LQ * TP_D * 4);
    u16* ctxB  = (u16*)take((size_t)TP_LQ * TP_D * 2);
    float* pre1  = (float*)take((size_t)TP_LQ * TP_D * 4);
    float* attn  = (float*)take((size_t)TP_LQ * TP_D * 4);
    u16* attnB = (u16*)take((size_t)TP_LQ * TP_D * 2);
    u16* hidden= (u16*)take((size_t)TP_LQ * TP_D4 * 2);
    float* pre2  = (float*)take((size_t)TP_LQ * TP_D * 4);
    float* colsum= (float*)take((size_t)TP_LK * 4);
    float* lsum  = (float*)take((size_t)TP_H * TP_LQ * 4);
    u16* E     = (u16*)take((size_t)TP_H * TP_LQ * TP_LK * 2);

    // ---- casts / transposes / zero-init
    cast_f32_bf16<<<(TP_LK * TP_D / 4 + 255) / 256, 256, 0, stream>>>(img, imgB, TP_LK * TP_D);
    cast_f32_bf16<<<(TP_LQ * TP_D / 4 + 255) / 256, 256, 0, stream>>>(mem, memB, TP_LQ * TP_D);
    transpose_cast<<<dim3(28, 28), dim3(32, 8), 0, stream>>>(qW, qWt, TP_D, TP_D);
    transpose_cast<<<dim3(28, 28), dim3(32, 8), 0, stream>>>(kW, kWt, TP_D, TP_D);
    transpose_cast<<<dim3(28, 28), dim3(32, 8), 0, stream>>>(vW, vWt, TP_D, TP_D);
    transpose_cast<<<dim3(28, 28), dim3(32, 8), 0, stream>>>(oW, oWt, TP_D, TP_D);
    transpose_cast<<<dim3(TP_D4 / 32, TP_D / 32), dim3(32, 8), 0, stream>>>(mW, mWt, TP_D, TP_D4);
    transpose_cast<<<dim3(TP_D / 32, TP_D4 / 32), dim3(32, 8), 0, stream>>>(pW, pWt, TP_D4, TP_D);
    hipMemsetAsync(colsum, 0, (size_t)TP_LK * 4, stream);
    hipMemsetAsync(lsum, 0, (size_t)TP_H * TP_LQ * 4, stream);
    hipMemsetAsync(ctxF, 0, (size_t)TP_LQ * TP_D * 4, stream);
    hipMemsetAsync(pre1, 0, (size_t)TP_LQ * TP_D * 4, stream);
    hipMemsetAsync(pre2, 0, (size_t)TP_LQ * TP_D * 4, stream);

    // ---- QKV projections
    {
        GemmParams p{};
        p.A = memB; p.aZ = 0; p.lda = TP_D;
        p.Bt = qWt; p.bZ = 0; p.ldb = TP_D;
        p.M = TP_LQ; p.N = TP_D; p.K = TP_D;
        p.bias = qb; p.outB = Qf; p.ldc = TP_D; p.relu = 0;
        gemm_bf16<4><<<dim3(7, 13, 1), 256, 0, stream>>>(p);
    }
    {
        GemmParams p{};
        p.A = imgB; p.aZ = 0; p.lda = TP_D;
        p.Bt = kWt; p.bZ = 0; p.ldb = TP_D;
        p.M = TP_LK; p.N = TP_D; p.K = TP_D;
        p.bias = kb; p.outB = Kf; p.ldc = TP_D; p.relu = 0;
        gemm_bf16<4><<<dim3(7, 49, 1), 256, 0, stream>>>(p);
    }
    {   // V-projection writing V^T [896][6272] directly
        GemmParams p{};
        p.A = imgB; p.aZ = 0; p.lda = TP_D;
        p.Bt = vWt; p.bZ = 0; p.ldb = TP_D;
        p.M = TP_LK; p.N = TP_D; p.K = TP_D;
        p.bias = vb; p.outB = Vtf; p.ldc = TP_LK;
        gemm_bf16<7><<<dim3(7, 49, 1), 256, 0, stream>>>(p);
    }

    // ---- fused attention (S + exp + E + l + PV), then colsum over E
    const float scale = 0.09449111825230679f;  // 1/sqrt(112)
    attn_fused<<<dim3(7, 13, TP_H), 256, 0, stream>>>(Qf, Kf, Vtf, E, lsum, ctxF, scale);
    colsum_kernel<<<dim3(7, 224), 256, 0, stream>>>(E, lsum, colsum, TP_H * TP_LQ);
    cast_div_bf16<<<(TP_LQ * TP_D / 4 + 255) / 256, 256, 0, stream>>>(ctxF, lsum, ctxB);

    // ---- O-projection split-K x2 -> pre1 (bias+residual in LN1)
    {
        GemmParams p{};
        p.A = ctxB; p.lda = TP_D;
        p.Bt = oWt; p.ldb = TP_D;
        p.M = TP_LQ; p.N = TP_D; p.K = 448; p.kc = 448;
        p.outF = pre1; p.ldc = TP_D;
        gemm_bf16<6><<<dim3(7, 13, 2), 256, 0, stream>>>(p);
    }
    layernorm_rows<<<TP_LQ, 256, 0, stream>>>(pre1, ob, mem, ln1g, ln1b, attn, attnB);

    // ---- MLP
    {
        GemmParams p{};
        p.A = attnB; p.aZ = 0; p.lda = TP_D;
        p.Bt = mWt; p.bZ = 0; p.ldb = TP_D;
        p.M = TP_LQ; p.N = TP_D4; p.K = TP_D;
        p.bias = mb; p.outB = hidden; p.ldc = TP_D4; p.relu = 1;
        gemm_bf16<4><<<dim3(28, 13, 1), 256, 0, stream>>>(p);
    }
    {   // MLP2 split-K x4 -> pre2 (bias+residual in LN2)
        GemmParams p{};
        p.A = hidden; p.lda = TP_D4;
        p.Bt = pWt; p.ldb = TP_D4;
        p.M = TP_LQ; p.N = TP_D; p.K = 896; p.kc = 896;
        p.outF = pre2; p.ldc = TP_D;
        gemm_bf16<6><<<dim3(7, 13, 4), 256, 0, stream>>>(p);
    }
    layernorm_rows<<<TP_LQ, 256, 0, stream>>>(pre2, pb, attn, ln2g, ln2b, out, nullptr);

    // ---- frame scores
    frame_scores_kernel<<<TP_F, 256, 0, stream>>>(colsum, out + (size_t)TP_LQ * TP_D);
}